// Round 1
// baseline (2988.037 us; speedup 1.0000x reference)
//
#include <hip/hip_runtime.h>
#include <math.h>

#define HIDDEN 128
#define NFILT 64

// ---------------------------------------------------------------------------
// Kernel 0: wsum[j] = sum_f Wf2[j][f]; bsum = sum_f bf2[f]
// (filters.sum(-1) collapses the [E,64]@[64,64] matmul to a 64-dot)
// ---------------------------------------------------------------------------
__global__ void wsum_kernel(const float* __restrict__ Wf2, const float* __restrict__ bf2,
                            float* __restrict__ wsum, float* __restrict__ bsum) {
    int j = threadIdx.x;  // 0..63
    float s = 0.f;
    for (int f = 0; f < NFILT; ++f) s += Wf2[j * NFILT + f];
    wsum[j] = s;
    if (j == 0) {
        float b = 0.f;
        for (int f = 0; f < NFILT; ++f) b += bf2[f];
        *bsum = b;
    }
}

// ---------------------------------------------------------------------------
// Kernel 1: per-edge scalar filter coefficient
// fs[e] = (bsum + sum_j tanh(s*Wf1[j]+bf1[j]) * wsum[j]) * cut(w)
// ---------------------------------------------------------------------------
__global__ void edge_filter_kernel(const float* __restrict__ ew,
                                   const float* __restrict__ Wf1, const float* __restrict__ bf1,
                                   const float* __restrict__ wsum, const float* __restrict__ bsum,
                                   float* __restrict__ fs, int E) {
    __shared__ float sW[NFILT], sB[NFILT], sS[NFILT];
    if (threadIdx.x < NFILT) {
        sW[threadIdx.x] = Wf1[threadIdx.x];
        sB[threadIdx.x] = bf1[threadIdx.x];
        sS[threadIdx.x] = wsum[threadIdx.x];
    }
    __syncthreads();
    int e = blockIdx.x * blockDim.x + threadIdx.x;
    if (e >= E) return;
    float w = ew[e];
    float s = fmaf(w, 0.25f, -1.0f);          // w * (2/8) - 1
    float acc = *bsum;
    #pragma unroll 8
    for (int j = 0; j < NFILT; ++j)
        acc += tanhf(fmaf(s, sW[j], sB[j])) * sS[j];
    // cut = 0.5*(cos(w*pi/8)+1), zeroed past cutoff
    float cut = (w <= 8.0f) ? 0.5f * (cosf(w * 0.39269908169872414f) + 1.0f) : 0.0f;
    fs[e] = acc * cut;
}

// ---------------------------------------------------------------------------
// Kernel 2: scatter  agg[row[e]][:] += x[col[e]][:] * fs[e]
// 32 lanes per edge, float4 per lane; agg lives in d_out (zeroed beforehand)
// ---------------------------------------------------------------------------
__global__ void scatter_kernel(const int* __restrict__ rows, const int* __restrict__ cols,
                               const float* __restrict__ x, const float* __restrict__ fs,
                               float* __restrict__ agg, int E) {
    int t = threadIdx.x;
    int e = blockIdx.x * 8 + (t >> 5);
    if (e >= E) return;
    int lane = t & 31;
    int r = rows[e];
    int c = cols[e];
    float f = fs[e];
    const float4 xv = *(const float4*)&x[c * HIDDEN + lane * 4];
    float* dst = &agg[r * HIDDEN + lane * 4];
    atomicAdd(dst + 0, xv.x * f);
    atomicAdd(dst + 1, xv.y * f);
    atomicAdd(dst + 2, xv.z * f);
    atomicAdd(dst + 3, xv.w * f);
}

// ---------------------------------------------------------------------------
// Kernel 3: fused node MLP, in-place on io=[N,128]:
//   out = BN( softplus(io @ Wi1 + bi1) @ Wi2 + bi2 )
// 64-row tile per block; W streamed in 64-row halves; LDS = 32K(A) + 32K(W)
// ---------------------------------------------------------------------------
__global__ __launch_bounds__(256) void mlp_kernel(
    float* __restrict__ io,
    const float* __restrict__ Wi1, const float* __restrict__ bi1,
    const float* __restrict__ Wi2, const float* __restrict__ bi2,
    const float* __restrict__ gamma, const float* __restrict__ beta,
    const float* __restrict__ mean, const float* __restrict__ var,
    int N) {
    __shared__ float As[64 * HIDDEN];   // A tile, later h tile
    __shared__ float Wh[64 * HIDDEN];   // half of W1/W2

    const int t = threadIdx.x;
    const int row0 = blockIdx.x * 64;
    const int col4 = (t & 31) * 4;      // this thread's 4 output cols
    const int rgrp = t >> 5;            // row group 0..7; rows rgrp + 8*r

    // load A tile (zero-padded past N)
    #pragma unroll
    for (int i = 0; i < 8; ++i) {
        int f4 = t + 256 * i;
        int r = f4 >> 5, c4 = (f4 & 31) * 4;
        int node = row0 + r;
        float4 v = make_float4(0.f, 0.f, 0.f, 0.f);
        if (node < N) v = *(const float4*)&io[node * HIDDEN + c4];
        *(float4*)&As[r * HIDDEN + c4] = v;
    }

    float acc[8][4];
    #pragma unroll
    for (int r = 0; r < 8; ++r)
        for (int j = 0; j < 4; ++j) acc[r][j] = 0.f;

    // ---- phase A: acc = A @ Wi1
    for (int kh = 0; kh < 2; ++kh) {
        __syncthreads();
        #pragma unroll
        for (int i = 0; i < 8; ++i) {
            int f4 = t + 256 * i;
            int kr = f4 >> 5, c4 = (f4 & 31) * 4;
            *(float4*)&Wh[kr * HIDDEN + c4] = *(const float4*)&Wi1[(kh * 64 + kr) * HIDDEN + c4];
        }
        __syncthreads();
        for (int k = 0; k < 64; ++k) {
            float4 w = *(const float4*)&Wh[k * HIDDEN + col4];
            #pragma unroll
            for (int r = 0; r < 8; ++r) {
                float a = As[(rgrp + 8 * r) * HIDDEN + kh * 64 + k];
                acc[r][0] = fmaf(a, w.x, acc[r][0]);
                acc[r][1] = fmaf(a, w.y, acc[r][1]);
                acc[r][2] = fmaf(a, w.z, acc[r][2]);
                acc[r][3] = fmaf(a, w.w, acc[r][3]);
            }
        }
    }
    __syncthreads();   // everyone done reading As/Wh

    // softplus epilogue -> h back into As
    {
        float4 b = *(const float4*)&bi1[col4];
        float bv[4] = {b.x, b.y, b.z, b.w};
        #pragma unroll
        for (int r = 0; r < 8; ++r) {
            float hv[4];
            #pragma unroll
            for (int j = 0; j < 4; ++j) {
                float v = acc[r][j] + bv[j];
                hv[j] = (v > 20.f) ? v : log1pf(__expf(v));
                acc[r][j] = 0.f;
            }
            *(float4*)&As[(rgrp + 8 * r) * HIDDEN + col4] =
                make_float4(hv[0], hv[1], hv[2], hv[3]);
        }
    }

    // ---- phase B: acc = h @ Wi2
    for (int kh = 0; kh < 2; ++kh) {
        __syncthreads();
        #pragma unroll
        for (int i = 0; i < 8; ++i) {
            int f4 = t + 256 * i;
            int kr = f4 >> 5, c4 = (f4 & 31) * 4;
            *(float4*)&Wh[kr * HIDDEN + c4] = *(const float4*)&Wi2[(kh * 64 + kr) * HIDDEN + c4];
        }
        __syncthreads();
        for (int k = 0; k < 64; ++k) {
            float4 w = *(const float4*)&Wh[k * HIDDEN + col4];
            #pragma unroll
            for (int r = 0; r < 8; ++r) {
                float a = As[(rgrp + 8 * r) * HIDDEN + kh * 64 + k];
                acc[r][0] = fmaf(a, w.x, acc[r][0]);
                acc[r][1] = fmaf(a, w.y, acc[r][1]);
                acc[r][2] = fmaf(a, w.z, acc[r][2]);
                acc[r][3] = fmaf(a, w.w, acc[r][3]);
            }
        }
    }

    // epilogue: + bi2, BatchNorm(inference), store
    {
        float4 b2 = *(const float4*)&bi2[col4];
        float4 g  = *(const float4*)&gamma[col4];
        float4 be = *(const float4*)&beta[col4];
        float4 mu = *(const float4*)&mean[col4];
        float4 va = *(const float4*)&var[col4];
        float bv[4] = {b2.x, b2.y, b2.z, b2.w};
        float gv[4] = {g.x, g.y, g.z, g.w};
        float bev[4] = {be.x, be.y, be.z, be.w};
        float muv[4] = {mu.x, mu.y, mu.z, mu.w};
        float sc[4];
        #pragma unroll
        for (int j = 0; j < 4; ++j) {
            float vav[4] = {va.x, va.y, va.z, va.w};
            sc[j] = gv[j] * rsqrtf(vav[j] + 1e-3f);
        }
        #pragma unroll
        for (int r = 0; r < 8; ++r) {
            int node = row0 + rgrp + 8 * r;
            if (node < N) {
                float o[4];
                #pragma unroll
                for (int j = 0; j < 4; ++j)
                    o[j] = (acc[r][j] + bv[j] - muv[j]) * sc[j] + bev[j];
                *(float4*)&io[node * HIDDEN + col4] = make_float4(o[0], o[1], o[2], o[3]);
            }
        }
    }
}

extern "C" void kernel_launch(void* const* d_in, const int* in_sizes, int n_in,
                              void* d_out, int out_size, void* d_ws, size_t ws_size,
                              hipStream_t stream) {
    const float* x    = (const float*)d_in[0];
    const int*   ei   = (const int*)d_in[1];
    const float* ew   = (const float*)d_in[2];
    // d_in[3] = edge_attr: unused by the reference math
    const float* Wf1  = (const float*)d_in[4];
    const float* bf1  = (const float*)d_in[5];
    const float* Wf2  = (const float*)d_in[6];
    const float* bf2  = (const float*)d_in[7];
    const float* Wi1  = (const float*)d_in[8];
    const float* bi1  = (const float*)d_in[9];
    const float* Wi2  = (const float*)d_in[10];
    const float* bi2  = (const float*)d_in[11];
    const float* gam  = (const float*)d_in[12];
    const float* bet  = (const float*)d_in[13];
    const float* mmu  = (const float*)d_in[14];
    const float* mva  = (const float*)d_in[15];

    const int N = in_sizes[0] / HIDDEN;
    const int E = in_sizes[2];
    const int* rows = ei;
    const int* cols = ei + E;

    float* ws_f = (float*)d_ws;
    float* fs   = ws_f;            // [E]
    float* wsum = ws_f + E;        // [64]
    float* bsum = ws_f + E + 64;   // [1]

    float* agg = (float*)d_out;    // agg lives in d_out; MLP runs in-place

    // zero the accumulator (d_out is poisoned 0xAA before every call)
    hipMemsetAsync(d_out, 0, (size_t)out_size * sizeof(float), stream);

    wsum_kernel<<<1, 64, 0, stream>>>(Wf2, bf2, wsum, bsum);

    edge_filter_kernel<<<(E + 255) / 256, 256, 0, stream>>>(ew, Wf1, bf1, wsum, bsum, fs, E);

    scatter_kernel<<<(E + 7) / 8, 256, 0, stream>>>(rows, cols, x, fs, agg, E);

    mlp_kernel<<<(N + 63) / 64, 256, 0, stream>>>(agg, Wi1, bi1, Wi2, bi2,
                                                  gam, bet, mmu, mva, N);
}

// Round 2
// 786.649 us; speedup vs baseline: 3.7984x; 3.7984x over previous
//
#include <hip/hip_runtime.h>
#include <math.h>

#define HIDDEN 128
#define NFILT 64

// ---------------------------------------------------------------------------
// Kernel 0: wsum[j] = sum_f Wf2[j][f]; bsum = sum_f bf2[f]
// (filters.sum(-1) collapses the [E,64]@[64,64] matmul to a 64-dot)
// ---------------------------------------------------------------------------
__global__ void wsum_kernel(const float* __restrict__ Wf2, const float* __restrict__ bf2,
                            float* __restrict__ wsum, float* __restrict__ bsum) {
    int j = threadIdx.x;  // 0..63
    float s = 0.f;
    for (int f = 0; f < NFILT; ++f) s += Wf2[j * NFILT + f];
    wsum[j] = s;
    if (j == 0) {
        float b = 0.f;
        for (int f = 0; f < NFILT; ++f) b += bf2[f];
        *bsum = b;
    }
}

__device__ __forceinline__ float edge_coeff(float w,
                                            const float* sW, const float* sB,
                                            const float* sS, float bsum) {
    float s = fmaf(w, 0.25f, -1.0f);          // w * (2/8) - 1
    float acc = bsum;
    #pragma unroll 8
    for (int j = 0; j < NFILT; ++j)
        acc += tanhf(fmaf(s, sW[j], sB[j])) * sS[j];
    float cut = (w <= 8.0f) ? 0.5f * (cosf(w * 0.39269908169872414f) + 1.0f) : 0.0f;
    return acc * cut;
}

// ---------------------------------------------------------------------------
// CSR build kernels
// ---------------------------------------------------------------------------
__global__ void count_kernel(const int* __restrict__ rows, int* __restrict__ deg, int E) {
    int e = blockIdx.x * blockDim.x + threadIdx.x;
    if (e < E) atomicAdd(&deg[rows[e]], 1);
}

// single-block exclusive scan over N elements (N ~ 100K): serial-per-thread +
// Hillis-Steele over 1024 partials. Writes offs[0..N] and cursor[0..N-1].
__global__ __launch_bounds__(1024) void scan_kernel(const int* __restrict__ deg,
                                                    int* __restrict__ offs,
                                                    int* __restrict__ cursor, int N) {
    __shared__ int part[1024];
    int t = threadIdx.x;
    int chunk = (N + 1023) / 1024;
    int s0 = t * chunk;
    int s1 = min(s0 + chunk, N);
    int sum = 0;
    for (int i = s0; i < s1; ++i) sum += deg[i];
    part[t] = sum;
    __syncthreads();
    for (int off = 1; off < 1024; off <<= 1) {
        int v = (t >= off) ? part[t - off] : 0;
        __syncthreads();
        part[t] += v;
        __syncthreads();
    }
    int run = (t == 0) ? 0 : part[t - 1];
    for (int i = s0; i < s1; ++i) {
        offs[i] = run;
        cursor[i] = run;
        run += deg[i];
    }
    if (t == 1023) offs[N] = part[1023];
}

// fill: compute edge coefficient (fused filter net) and drop (col, f) into CSR slot
__global__ void fill_kernel(const int* __restrict__ rows, const int* __restrict__ cols,
                            const float* __restrict__ ew,
                            const float* __restrict__ Wf1, const float* __restrict__ bf1,
                            const float* __restrict__ wsum, const float* __restrict__ bsum,
                            int* __restrict__ cursor, int2* __restrict__ epack, int E) {
    __shared__ float sW[NFILT], sB[NFILT], sS[NFILT];
    if (threadIdx.x < NFILT) {
        sW[threadIdx.x] = Wf1[threadIdx.x];
        sB[threadIdx.x] = bf1[threadIdx.x];
        sS[threadIdx.x] = wsum[threadIdx.x];
    }
    __syncthreads();
    int e = blockIdx.x * blockDim.x + threadIdx.x;
    if (e >= E) return;
    float f = edge_coeff(ew[e], sW, sB, sS, *bsum);
    int r = rows[e];
    int pos = atomicAdd(&cursor[r], 1);
    epack[pos] = make_int2(cols[e], __float_as_int(f));
}

// gather: 32 lanes per node; acc[node][:] = sum over its edges x[col]*f
__global__ __launch_bounds__(256) void gather_kernel(const int* __restrict__ offs,
                                                     const int2* __restrict__ epack,
                                                     const float* __restrict__ x,
                                                     float* __restrict__ agg, int N) {
    int t = threadIdx.x;
    int node = blockIdx.x * 8 + (t >> 5);
    if (node >= N) return;
    int lane = t & 31;
    int s = offs[node], eend = offs[node + 1];
    float4 acc = make_float4(0.f, 0.f, 0.f, 0.f);
    for (int i = s; i < eend; ++i) {
        int2 p = epack[i];
        float f = __int_as_float(p.y);
        const float4 xv = *(const float4*)&x[(size_t)p.x * HIDDEN + lane * 4];
        acc.x = fmaf(xv.x, f, acc.x);
        acc.y = fmaf(xv.y, f, acc.y);
        acc.z = fmaf(xv.z, f, acc.z);
        acc.w = fmaf(xv.w, f, acc.w);
    }
    *(float4*)&agg[(size_t)node * HIDDEN + lane * 4] = acc;
}

// ---------------------------------------------------------------------------
// Fallback path (small ws): per-edge fs + atomic scatter (round-1 kernels)
// ---------------------------------------------------------------------------
__global__ void edge_filter_kernel(const float* __restrict__ ew,
                                   const float* __restrict__ Wf1, const float* __restrict__ bf1,
                                   const float* __restrict__ wsum, const float* __restrict__ bsum,
                                   float* __restrict__ fs, int E) {
    __shared__ float sW[NFILT], sB[NFILT], sS[NFILT];
    if (threadIdx.x < NFILT) {
        sW[threadIdx.x] = Wf1[threadIdx.x];
        sB[threadIdx.x] = bf1[threadIdx.x];
        sS[threadIdx.x] = wsum[threadIdx.x];
    }
    __syncthreads();
    int e = blockIdx.x * blockDim.x + threadIdx.x;
    if (e >= E) return;
    fs[e] = edge_coeff(ew[e], sW, sB, sS, *bsum);
}

__global__ void scatter_kernel(const int* __restrict__ rows, const int* __restrict__ cols,
                               const float* __restrict__ x, const float* __restrict__ fs,
                               float* __restrict__ agg, int E) {
    int t = threadIdx.x;
    int e = blockIdx.x * 8 + (t >> 5);
    if (e >= E) return;
    int lane = t & 31;
    int r = rows[e];
    int c = cols[e];
    float f = fs[e];
    const float4 xv = *(const float4*)&x[c * HIDDEN + lane * 4];
    float* dst = &agg[r * HIDDEN + lane * 4];
    atomicAdd(dst + 0, xv.x * f);
    atomicAdd(dst + 1, xv.y * f);
    atomicAdd(dst + 2, xv.z * f);
    atomicAdd(dst + 3, xv.w * f);
}

// ---------------------------------------------------------------------------
// Kernel 3: fused node MLP, in-place on io=[N,128]:
//   out = BN( softplus(io @ Wi1 + bi1) @ Wi2 + bi2 )
// 64-row tile per block; W streamed in 64-row halves; LDS = 32K(A) + 32K(W)
// ---------------------------------------------------------------------------
__global__ __launch_bounds__(256) void mlp_kernel(
    float* __restrict__ io,
    const float* __restrict__ Wi1, const float* __restrict__ bi1,
    const float* __restrict__ Wi2, const float* __restrict__ bi2,
    const float* __restrict__ gamma, const float* __restrict__ beta,
    const float* __restrict__ mean, const float* __restrict__ var,
    int N) {
    __shared__ float As[64 * HIDDEN];   // A tile, later h tile
    __shared__ float Wh[64 * HIDDEN];   // half of W1/W2

    const int t = threadIdx.x;
    const int row0 = blockIdx.x * 64;
    const int col4 = (t & 31) * 4;      // this thread's 4 output cols
    const int rgrp = t >> 5;            // row group 0..7; rows rgrp + 8*r

    #pragma unroll
    for (int i = 0; i < 8; ++i) {
        int f4 = t + 256 * i;
        int r = f4 >> 5, c4 = (f4 & 31) * 4;
        int node = row0 + r;
        float4 v = make_float4(0.f, 0.f, 0.f, 0.f);
        if (node < N) v = *(const float4*)&io[node * HIDDEN + c4];
        *(float4*)&As[r * HIDDEN + c4] = v;
    }

    float acc[8][4];
    #pragma unroll
    for (int r = 0; r < 8; ++r)
        for (int j = 0; j < 4; ++j) acc[r][j] = 0.f;

    // ---- phase A: acc = A @ Wi1
    for (int kh = 0; kh < 2; ++kh) {
        __syncthreads();
        #pragma unroll
        for (int i = 0; i < 8; ++i) {
            int f4 = t + 256 * i;
            int kr = f4 >> 5, c4 = (f4 & 31) * 4;
            *(float4*)&Wh[kr * HIDDEN + c4] = *(const float4*)&Wi1[(kh * 64 + kr) * HIDDEN + c4];
        }
        __syncthreads();
        for (int k = 0; k < 64; ++k) {
            float4 w = *(const float4*)&Wh[k * HIDDEN + col4];
            #pragma unroll
            for (int r = 0; r < 8; ++r) {
                float a = As[(rgrp + 8 * r) * HIDDEN + kh * 64 + k];
                acc[r][0] = fmaf(a, w.x, acc[r][0]);
                acc[r][1] = fmaf(a, w.y, acc[r][1]);
                acc[r][2] = fmaf(a, w.z, acc[r][2]);
                acc[r][3] = fmaf(a, w.w, acc[r][3]);
            }
        }
    }
    __syncthreads();

    {
        float4 b = *(const float4*)&bi1[col4];
        float bv[4] = {b.x, b.y, b.z, b.w};
        #pragma unroll
        for (int r = 0; r < 8; ++r) {
            float hv[4];
            #pragma unroll
            for (int j = 0; j < 4; ++j) {
                float v = acc[r][j] + bv[j];
                hv[j] = (v > 20.f) ? v : log1pf(__expf(v));
                acc[r][j] = 0.f;
            }
            *(float4*)&As[(rgrp + 8 * r) * HIDDEN + col4] =
                make_float4(hv[0], hv[1], hv[2], hv[3]);
        }
    }

    // ---- phase B: acc = h @ Wi2
    for (int kh = 0; kh < 2; ++kh) {
        __syncthreads();
        #pragma unroll
        for (int i = 0; i < 8; ++i) {
            int f4 = t + 256 * i;
            int kr = f4 >> 5, c4 = (f4 & 31) * 4;
            *(float4*)&Wh[kr * HIDDEN + c4] = *(const float4*)&Wi2[(kh * 64 + kr) * HIDDEN + c4];
        }
        __syncthreads();
        for (int k = 0; k < 64; ++k) {
            float4 w = *(const float4*)&Wh[k * HIDDEN + col4];
            #pragma unroll
            for (int r = 0; r < 8; ++r) {
                float a = As[(rgrp + 8 * r) * HIDDEN + kh * 64 + k];
                acc[r][0] = fmaf(a, w.x, acc[r][0]);
                acc[r][1] = fmaf(a, w.y, acc[r][1]);
                acc[r][2] = fmaf(a, w.z, acc[r][2]);
                acc[r][3] = fmaf(a, w.w, acc[r][3]);
            }
        }
    }

    {
        float4 b2 = *(const float4*)&bi2[col4];
        float4 g  = *(const float4*)&gamma[col4];
        float4 be = *(const float4*)&beta[col4];
        float4 mu = *(const float4*)&mean[col4];
        float4 va = *(const float4*)&var[col4];
        float bv[4]  = {b2.x, b2.y, b2.z, b2.w};
        float gv[4]  = {g.x, g.y, g.z, g.w};
        float bev[4] = {be.x, be.y, be.z, be.w};
        float muv[4] = {mu.x, mu.y, mu.z, mu.w};
        float vav[4] = {va.x, va.y, va.z, va.w};
        float sc[4];
        #pragma unroll
        for (int j = 0; j < 4; ++j) sc[j] = gv[j] * rsqrtf(vav[j] + 1e-3f);
        #pragma unroll
        for (int r = 0; r < 8; ++r) {
            int node = row0 + rgrp + 8 * r;
            if (node < N) {
                float o[4];
                #pragma unroll
                for (int j = 0; j < 4; ++j)
                    o[j] = (acc[r][j] + bv[j] - muv[j]) * sc[j] + bev[j];
                *(float4*)&io[node * HIDDEN + col4] = make_float4(o[0], o[1], o[2], o[3]);
            }
        }
    }
}

extern "C" void kernel_launch(void* const* d_in, const int* in_sizes, int n_in,
                              void* d_out, int out_size, void* d_ws, size_t ws_size,
                              hipStream_t stream) {
    const float* x    = (const float*)d_in[0];
    const int*   ei   = (const int*)d_in[1];
    const float* ew   = (const float*)d_in[2];
    // d_in[3] = edge_attr: unused by the reference math
    const float* Wf1  = (const float*)d_in[4];
    const float* bf1  = (const float*)d_in[5];
    const float* Wf2  = (const float*)d_in[6];
    const float* bf2  = (const float*)d_in[7];
    const float* Wi1  = (const float*)d_in[8];
    const float* bi1  = (const float*)d_in[9];
    const float* Wi2  = (const float*)d_in[10];
    const float* bi2  = (const float*)d_in[11];
    const float* gam  = (const float*)d_in[12];
    const float* bet  = (const float*)d_in[13];
    const float* mmu  = (const float*)d_in[14];
    const float* mva  = (const float*)d_in[15];

    const int N = in_sizes[0] / HIDDEN;
    const int E = in_sizes[2];
    const int* rows = ei;
    const int* cols = ei + E;

    float* agg = (float*)d_out;    // agg lives in d_out; MLP runs in-place

    // ws layout (CSR path):
    //   deg[N] | offs[N+1] | cursor[N] | wsum[64] | bsum[1] | pad | epack[E] (int2)
    char* ws = (char*)d_ws;
    int*   deg    = (int*)ws;
    int*   offs   = deg + N;
    int*   cursor = offs + N + 1;
    float* wsumv  = (float*)(cursor + N);
    float* bsumv  = wsumv + NFILT;
    size_t epack_off = (((size_t)(3 * N + 1 + NFILT + 1) * 4) + 15) & ~(size_t)15;
    int2*  epack  = (int2*)(ws + epack_off);
    size_t need   = epack_off + (size_t)E * sizeof(int2);

    if (ws_size >= need) {
        // ---- CSR path: no fp32 atomics ----
        hipMemsetAsync(deg, 0, (size_t)N * sizeof(int), stream);
        wsum_kernel<<<1, 64, 0, stream>>>(Wf2, bf2, wsumv, bsumv);
        count_kernel<<<(E + 255) / 256, 256, 0, stream>>>(rows, deg, E);
        scan_kernel<<<1, 1024, 0, stream>>>(deg, offs, cursor, N);
        fill_kernel<<<(E + 255) / 256, 256, 0, stream>>>(rows, cols, ew, Wf1, bf1,
                                                         wsumv, bsumv, cursor, epack, E);
        gather_kernel<<<(N + 7) / 8, 256, 0, stream>>>(offs, epack, x, agg, N);
    } else {
        // ---- fallback: atomic scatter ----
        float* fs = (float*)d_ws;             // [E]
        float* w2 = fs + E;                   // [64]
        float* b2 = w2 + NFILT;               // [1]
        hipMemsetAsync(d_out, 0, (size_t)out_size * sizeof(float), stream);
        wsum_kernel<<<1, 64, 0, stream>>>(Wf2, bf2, w2, b2);
        edge_filter_kernel<<<(E + 255) / 256, 256, 0, stream>>>(ew, Wf1, bf1, w2, b2, fs, E);
        scatter_kernel<<<(E + 7) / 8, 256, 0, stream>>>(rows, cols, x, fs, agg, E);
    }

    mlp_kernel<<<(N + 63) / 64, 256, 0, stream>>>(agg, Wi1, bi1, Wi2, bi2,
                                                  gam, bet, mmu, mva, N);
}

// Round 3
// 565.723 us; speedup vs baseline: 5.2818x; 1.3905x over previous
//
#include <hip/hip_runtime.h>
#include <math.h>

#define HIDDEN 128
#define NFILT 64
#define SCAN_B 1024

// ---------------------------------------------------------------------------
// Kernel 0: wsum[j] = sum_f Wf2[j][f]; bsum = sum_f bf2[f]
// (filters.sum(-1) collapses the [E,64]@[64,64] matmul to a 64-dot)
// ---------------------------------------------------------------------------
__global__ void wsum_kernel(const float* __restrict__ Wf2, const float* __restrict__ bf2,
                            float* __restrict__ wsum, float* __restrict__ bsum) {
    int j = threadIdx.x;  // 0..63
    float s = 0.f;
    for (int f = 0; f < NFILT; ++f) s += Wf2[j * NFILT + f];
    wsum[j] = s;
    if (j == 0) {
        float b = 0.f;
        for (int f = 0; f < NFILT; ++f) b += bf2[f];
        *bsum = b;
    }
}

__device__ __forceinline__ float edge_coeff(float w,
                                            const float* sW, const float* sB,
                                            const float* sS, float bsum) {
    float s = fmaf(w, 0.25f, -1.0f);          // w * (2/8) - 1
    float acc = bsum;
    #pragma unroll 8
    for (int j = 0; j < NFILT; ++j)
        acc += tanhf(fmaf(s, sW[j], sB[j])) * sS[j];
    float cut = (w <= 8.0f) ? 0.5f * (cosf(w * 0.39269908169872414f) + 1.0f) : 0.0f;
    return acc * cut;
}

// ---------------------------------------------------------------------------
// CSR build kernels
// ---------------------------------------------------------------------------
__global__ void count_kernel(const int* __restrict__ rows, int* __restrict__ deg, int E) {
    int e = blockIdx.x * blockDim.x + threadIdx.x;
    if (e < E) atomicAdd(&deg[rows[e]], 1);
}

// ---- 3-phase device-wide exclusive scan over deg[N] -> offs[N+1], cursor[N]
// phase 1: per-block sums
__global__ __launch_bounds__(SCAN_B) void scan_p1(const int* __restrict__ deg,
                                                  int* __restrict__ bsums, int N) {
    __shared__ int red[SCAN_B];
    int i = blockIdx.x * SCAN_B + threadIdx.x;
    red[threadIdx.x] = (i < N) ? deg[i] : 0;
    __syncthreads();
    for (int off = SCAN_B / 2; off > 0; off >>= 1) {
        if (threadIdx.x < off) red[threadIdx.x] += red[threadIdx.x + off];
        __syncthreads();
    }
    if (threadIdx.x == 0) bsums[blockIdx.x] = red[0];
}

// phase 2: exclusive scan of B block sums (B <= 1024), single block
__global__ __launch_bounds__(SCAN_B) void scan_p2(int* __restrict__ bsums, int B) {
    __shared__ int part[SCAN_B];
    int t = threadIdx.x;
    part[t] = (t < B) ? bsums[t] : 0;
    __syncthreads();
    for (int off = 1; off < SCAN_B; off <<= 1) {
        int v = (t >= off) ? part[t - off] : 0;
        __syncthreads();
        part[t] += v;
        __syncthreads();
    }
    if (t < B) bsums[t] = (t == 0) ? 0 : part[t - 1];   // exclusive
}

// phase 3: block-local exclusive scan + block prefix; write offs & cursor
__global__ __launch_bounds__(SCAN_B) void scan_p3(const int* __restrict__ deg,
                                                  const int* __restrict__ bsums,
                                                  int* __restrict__ offs,
                                                  int* __restrict__ cursor, int N) {
    __shared__ int part[SCAN_B];
    int t = threadIdx.x;
    int i = blockIdx.x * SCAN_B + t;
    int d = (i < N) ? deg[i] : 0;
    part[t] = d;
    __syncthreads();
    for (int off = 1; off < SCAN_B; off <<= 1) {
        int v = (t >= off) ? part[t - off] : 0;
        __syncthreads();
        part[t] += v;
        __syncthreads();
    }
    int pre = bsums[blockIdx.x] + part[t] - d;   // exclusive prefix for i
    if (i < N) {
        offs[i] = pre;
        cursor[i] = pre;
        if (i == N - 1) offs[N] = pre + d;
    }
}

// fill: compute edge coefficient (fused filter net) and drop (col, f) into CSR slot
__global__ void fill_kernel(const int* __restrict__ rows, const int* __restrict__ cols,
                            const float* __restrict__ ew,
                            const float* __restrict__ Wf1, const float* __restrict__ bf1,
                            const float* __restrict__ wsum, const float* __restrict__ bsum,
                            int* __restrict__ cursor, int2* __restrict__ epack, int E) {
    __shared__ float sW[NFILT], sB[NFILT], sS[NFILT];
    if (threadIdx.x < NFILT) {
        sW[threadIdx.x] = Wf1[threadIdx.x];
        sB[threadIdx.x] = bf1[threadIdx.x];
        sS[threadIdx.x] = wsum[threadIdx.x];
    }
    __syncthreads();
    int e = blockIdx.x * blockDim.x + threadIdx.x;
    if (e >= E) return;
    float f = edge_coeff(ew[e], sW, sB, sS, *bsum);
    int r = rows[e];
    int pos = atomicAdd(&cursor[r], 1);
    epack[pos] = make_int2(cols[e], __float_as_int(f));
}

// gather: 32 lanes per node; acc[node][:] = sum over its edges x[col]*f
__global__ __launch_bounds__(256) void gather_kernel(const int* __restrict__ offs,
                                                     const int2* __restrict__ epack,
                                                     const float* __restrict__ x,
                                                     float* __restrict__ agg, int N) {
    int t = threadIdx.x;
    int node = blockIdx.x * 8 + (t >> 5);
    if (node >= N) return;
    int lane = t & 31;
    int s = offs[node], eend = offs[node + 1];
    float4 acc = make_float4(0.f, 0.f, 0.f, 0.f);
    for (int i = s; i < eend; ++i) {
        int2 p = epack[i];
        float f = __int_as_float(p.y);
        const float4 xv = *(const float4*)&x[(size_t)p.x * HIDDEN + lane * 4];
        acc.x = fmaf(xv.x, f, acc.x);
        acc.y = fmaf(xv.y, f, acc.y);
        acc.z = fmaf(xv.z, f, acc.z);
        acc.w = fmaf(xv.w, f, acc.w);
    }
    *(float4*)&agg[(size_t)node * HIDDEN + lane * 4] = acc;
}

// ---------------------------------------------------------------------------
// Fallback path (small ws): per-edge fs + atomic scatter (round-1 kernels)
// ---------------------------------------------------------------------------
__global__ void edge_filter_kernel(const float* __restrict__ ew,
                                   const float* __restrict__ Wf1, const float* __restrict__ bf1,
                                   const float* __restrict__ wsum, const float* __restrict__ bsum,
                                   float* __restrict__ fs, int E) {
    __shared__ float sW[NFILT], sB[NFILT], sS[NFILT];
    if (threadIdx.x < NFILT) {
        sW[threadIdx.x] = Wf1[threadIdx.x];
        sB[threadIdx.x] = bf1[threadIdx.x];
        sS[threadIdx.x] = wsum[threadIdx.x];
    }
    __syncthreads();
    int e = blockIdx.x * blockDim.x + threadIdx.x;
    if (e >= E) return;
    fs[e] = edge_coeff(ew[e], sW, sB, sS, *bsum);
}

__global__ void scatter_kernel(const int* __restrict__ rows, const int* __restrict__ cols,
                               const float* __restrict__ x, const float* __restrict__ fs,
                               float* __restrict__ agg, int E) {
    int t = threadIdx.x;
    int e = blockIdx.x * 8 + (t >> 5);
    if (e >= E) return;
    int lane = t & 31;
    int r = rows[e];
    int c = cols[e];
    float f = fs[e];
    const float4 xv = *(const float4*)&x[c * HIDDEN + lane * 4];
    float* dst = &agg[r * HIDDEN + lane * 4];
    atomicAdd(dst + 0, xv.x * f);
    atomicAdd(dst + 1, xv.y * f);
    atomicAdd(dst + 2, xv.z * f);
    atomicAdd(dst + 3, xv.w * f);
}

// ---------------------------------------------------------------------------
// Kernel 3: fused node MLP, in-place on io=[N,128]:
//   out = BN( softplus(io @ Wi1 + bi1) @ Wi2 + bi2 )
// 64-row tile per block; W streamed in 64-row halves; LDS = 32K(A) + 32K(W)
// ---------------------------------------------------------------------------
__global__ __launch_bounds__(256) void mlp_kernel(
    float* __restrict__ io,
    const float* __restrict__ Wi1, const float* __restrict__ bi1,
    const float* __restrict__ Wi2, const float* __restrict__ bi2,
    const float* __restrict__ gamma, const float* __restrict__ beta,
    const float* __restrict__ mean, const float* __restrict__ var,
    int N) {
    __shared__ float As[64 * HIDDEN];   // A tile, later h tile
    __shared__ float Wh[64 * HIDDEN];   // half of W1/W2

    const int t = threadIdx.x;
    const int row0 = blockIdx.x * 64;
    const int col4 = (t & 31) * 4;      // this thread's 4 output cols
    const int rgrp = t >> 5;            // row group 0..7; rows rgrp + 8*r

    #pragma unroll
    for (int i = 0; i < 8; ++i) {
        int f4 = t + 256 * i;
        int r = f4 >> 5, c4 = (f4 & 31) * 4;
        int node = row0 + r;
        float4 v = make_float4(0.f, 0.f, 0.f, 0.f);
        if (node < N) v = *(const float4*)&io[node * HIDDEN + c4];
        *(float4*)&As[r * HIDDEN + c4] = v;
    }

    float acc[8][4];
    #pragma unroll
    for (int r = 0; r < 8; ++r)
        for (int j = 0; j < 4; ++j) acc[r][j] = 0.f;

    // ---- phase A: acc = A @ Wi1
    for (int kh = 0; kh < 2; ++kh) {
        __syncthreads();
        #pragma unroll
        for (int i = 0; i < 8; ++i) {
            int f4 = t + 256 * i;
            int kr = f4 >> 5, c4 = (f4 & 31) * 4;
            *(float4*)&Wh[kr * HIDDEN + c4] = *(const float4*)&Wi1[(kh * 64 + kr) * HIDDEN + c4];
        }
        __syncthreads();
        for (int k = 0; k < 64; ++k) {
            float4 w = *(const float4*)&Wh[k * HIDDEN + col4];
            #pragma unroll
            for (int r = 0; r < 8; ++r) {
                float a = As[(rgrp + 8 * r) * HIDDEN + kh * 64 + k];
                acc[r][0] = fmaf(a, w.x, acc[r][0]);
                acc[r][1] = fmaf(a, w.y, acc[r][1]);
                acc[r][2] = fmaf(a, w.z, acc[r][2]);
                acc[r][3] = fmaf(a, w.w, acc[r][3]);
            }
        }
    }
    __syncthreads();

    {
        float4 b = *(const float4*)&bi1[col4];
        float bv[4] = {b.x, b.y, b.z, b.w};
        #pragma unroll
        for (int r = 0; r < 8; ++r) {
            float hv[4];
            #pragma unroll
            for (int j = 0; j < 4; ++j) {
                float v = acc[r][j] + bv[j];
                hv[j] = (v > 20.f) ? v : log1pf(__expf(v));
                acc[r][j] = 0.f;
            }
            *(float4*)&As[(rgrp + 8 * r) * HIDDEN + col4] =
                make_float4(hv[0], hv[1], hv[2], hv[3]);
        }
    }

    // ---- phase B: acc = h @ Wi2
    for (int kh = 0; kh < 2; ++kh) {
        __syncthreads();
        #pragma unroll
        for (int i = 0; i < 8; ++i) {
            int f4 = t + 256 * i;
            int kr = f4 >> 5, c4 = (f4 & 31) * 4;
            *(float4*)&Wh[kr * HIDDEN + c4] = *(const float4*)&Wi2[(kh * 64 + kr) * HIDDEN + c4];
        }
        __syncthreads();
        for (int k = 0; k < 64; ++k) {
            float4 w = *(const float4*)&Wh[k * HIDDEN + col4];
            #pragma unroll
            for (int r = 0; r < 8; ++r) {
                float a = As[(rgrp + 8 * r) * HIDDEN + kh * 64 + k];
                acc[r][0] = fmaf(a, w.x, acc[r][0]);
                acc[r][1] = fmaf(a, w.y, acc[r][1]);
                acc[r][2] = fmaf(a, w.z, acc[r][2]);
                acc[r][3] = fmaf(a, w.w, acc[r][3]);
            }
        }
    }

    {
        float4 b2 = *(const float4*)&bi2[col4];
        float4 g  = *(const float4*)&gamma[col4];
        float4 be = *(const float4*)&beta[col4];
        float4 mu = *(const float4*)&mean[col4];
        float4 va = *(const float4*)&var[col4];
        float bv[4]  = {b2.x, b2.y, b2.z, b2.w};
        float gv[4]  = {g.x, g.y, g.z, g.w};
        float bev[4] = {be.x, be.y, be.z, be.w};
        float muv[4] = {mu.x, mu.y, mu.z, mu.w};
        float vav[4] = {va.x, va.y, va.z, va.w};
        float sc[4];
        #pragma unroll
        for (int j = 0; j < 4; ++j) sc[j] = gv[j] * rsqrtf(vav[j] + 1e-3f);
        #pragma unroll
        for (int r = 0; r < 8; ++r) {
            int node = row0 + rgrp + 8 * r;
            if (node < N) {
                float o[4];
                #pragma unroll
                for (int j = 0; j < 4; ++j)
                    o[j] = (acc[r][j] + bv[j] - muv[j]) * sc[j] + bev[j];
                *(float4*)&io[node * HIDDEN + col4] = make_float4(o[0], o[1], o[2], o[3]);
            }
        }
    }
}

extern "C" void kernel_launch(void* const* d_in, const int* in_sizes, int n_in,
                              void* d_out, int out_size, void* d_ws, size_t ws_size,
                              hipStream_t stream) {
    const float* x    = (const float*)d_in[0];
    const int*   ei   = (const int*)d_in[1];
    const float* ew   = (const float*)d_in[2];
    // d_in[3] = edge_attr: unused by the reference math
    const float* Wf1  = (const float*)d_in[4];
    const float* bf1  = (const float*)d_in[5];
    const float* Wf2  = (const float*)d_in[6];
    const float* bf2  = (const float*)d_in[7];
    const float* Wi1  = (const float*)d_in[8];
    const float* bi1  = (const float*)d_in[9];
    const float* Wi2  = (const float*)d_in[10];
    const float* bi2  = (const float*)d_in[11];
    const float* gam  = (const float*)d_in[12];
    const float* bet  = (const float*)d_in[13];
    const float* mmu  = (const float*)d_in[14];
    const float* mva  = (const float*)d_in[15];

    const int N = in_sizes[0] / HIDDEN;
    const int E = in_sizes[2];
    const int* rows = ei;
    const int* cols = ei + E;

    float* agg = (float*)d_out;    // agg lives in d_out; MLP runs in-place

    const int B = (N + SCAN_B - 1) / SCAN_B;   // scan blocks (<= 1024 supported)

    // ws layout (CSR path):
    //   deg[N] | offs[N+1] | cursor[N] | bsums[B] | wsum[64] | bsum[1] | pad | epack[E]
    char* ws = (char*)d_ws;
    int*   deg    = (int*)ws;
    int*   offs   = deg + N;
    int*   cursor = offs + N + 1;
    int*   bsums  = cursor + N;
    float* wsumv  = (float*)(bsums + B);
    float* bsumv  = wsumv + NFILT;
    size_t epack_off = (((size_t)(3 * N + 1 + B + NFILT + 1) * 4) + 15) & ~(size_t)15;
    int2*  epack  = (int2*)(ws + epack_off);
    size_t need   = epack_off + (size_t)E * sizeof(int2);

    if (ws_size >= need && B <= SCAN_B) {
        // ---- CSR path: no fp32 atomics ----
        hipMemsetAsync(deg, 0, (size_t)N * sizeof(int), stream);
        wsum_kernel<<<1, 64, 0, stream>>>(Wf2, bf2, wsumv, bsumv);
        count_kernel<<<(E + 255) / 256, 256, 0, stream>>>(rows, deg, E);
        scan_p1<<<B, SCAN_B, 0, stream>>>(deg, bsums, N);
        scan_p2<<<1, SCAN_B, 0, stream>>>(bsums, B);
        scan_p3<<<B, SCAN_B, 0, stream>>>(deg, bsums, offs, cursor, N);
        fill_kernel<<<(E + 255) / 256, 256, 0, stream>>>(rows, cols, ew, Wf1, bf1,
                                                         wsumv, bsumv, cursor, epack, E);
        gather_kernel<<<(N + 7) / 8, 256, 0, stream>>>(offs, epack, x, agg, N);
    } else {
        // ---- fallback: atomic scatter ----
        float* fs = (float*)d_ws;             // [E]
        float* w2 = fs + E;                   // [64]
        float* b2 = w2 + NFILT;               // [1]
        hipMemsetAsync(d_out, 0, (size_t)out_size * sizeof(float), stream);
        wsum_kernel<<<1, 64, 0, stream>>>(Wf2, bf2, w2, b2);
        edge_filter_kernel<<<(E + 255) / 256, 256, 0, stream>>>(ew, Wf1, bf1, w2, b2, fs, E);
        scatter_kernel<<<(E + 7) / 8, 256, 0, stream>>>(rows, cols, x, fs, agg, E);
    }

    mlp_kernel<<<(N + 63) / 64, 256, 0, stream>>>(agg, Wi1, bi1, Wi2, bi2,
                                                  gam, bet, mmu, mva, N);
}

// Round 4
// 522.698 us; speedup vs baseline: 5.7166x; 1.0823x over previous
//
#include <hip/hip_runtime.h>
#include <math.h>

#define HIDDEN 128
#define NFILT 64
#define SCAN_B 1024

typedef __attribute__((ext_vector_type(8))) short bf16x8;
typedef __attribute__((ext_vector_type(4))) float f32x4;

__device__ __forceinline__ short f2bf(float f) {
    unsigned u = __float_as_uint(f);
    unsigned r = (u + 0x7fffu + ((u >> 16) & 1u)) >> 16;   // RNE
    return (short)r;
}

// ---------------------------------------------------------------------------
// Kernel 0: wsum[j] = sum_f Wf2[j][f]; bsum = sum_f bf2[f]
// ---------------------------------------------------------------------------
__global__ void wsum_kernel(const float* __restrict__ Wf2, const float* __restrict__ bf2,
                            float* __restrict__ wsum, float* __restrict__ bsum) {
    int j = threadIdx.x;  // 0..63
    float s = 0.f;
    for (int f = 0; f < NFILT; ++f) s += Wf2[j * NFILT + f];
    wsum[j] = s;
    if (j == 0) {
        float b = 0.f;
        for (int f = 0; f < NFILT; ++f) b += bf2[f];
        *bsum = b;
    }
}

__device__ __forceinline__ float edge_coeff(float w,
                                            const float* sW, const float* sB,
                                            const float* sS, float bsum) {
    float s = fmaf(w, 0.25f, -1.0f);          // w * (2/8) - 1
    float acc = bsum;
    #pragma unroll 8
    for (int j = 0; j < NFILT; ++j)
        acc += tanhf(fmaf(s, sW[j], sB[j])) * sS[j];
    float cut = (w <= 8.0f) ? 0.5f * (cosf(w * 0.39269908169872414f) + 1.0f) : 0.0f;
    return acc * cut;
}

// ---------------------------------------------------------------------------
// Prep: W1T/W2T = bf16 transpose of Wi1/Wi2; BN folded into scale/shift
// ---------------------------------------------------------------------------
__global__ void prep_w_kernel(const float* __restrict__ Wi1, const float* __restrict__ Wi2,
                              short* __restrict__ W1T, short* __restrict__ W2T) {
    int idx = blockIdx.x * 256 + threadIdx.x;   // 0..32767
    const float* src = (idx < 16384) ? Wi1 : Wi2;
    short* dst = (idx < 16384) ? W1T : W2T;
    int i = idx & 16383;
    int k = i >> 7, n = i & 127;
    dst[n * HIDDEN + k] = f2bf(src[i]);
}

__global__ void prep_bn_kernel(const float* __restrict__ bi2,
                               const float* __restrict__ gamma, const float* __restrict__ beta,
                               const float* __restrict__ mean, const float* __restrict__ var,
                               float* __restrict__ scf, float* __restrict__ shf) {
    int j = threadIdx.x;  // 0..127
    float sc = gamma[j] * rsqrtf(var[j] + 1e-3f);
    scf[j] = sc;
    shf[j] = (bi2[j] - mean[j]) * sc + beta[j];
}

// ---------------------------------------------------------------------------
// CSR build kernels
// ---------------------------------------------------------------------------
__global__ void count_kernel(const int* __restrict__ rows, int* __restrict__ deg, int E) {
    int e = blockIdx.x * blockDim.x + threadIdx.x;
    if (e < E) atomicAdd(&deg[rows[e]], 1);
}

__global__ __launch_bounds__(SCAN_B) void scan_p1(const int* __restrict__ deg,
                                                  int* __restrict__ bsums, int N) {
    __shared__ int red[SCAN_B];
    int i = blockIdx.x * SCAN_B + threadIdx.x;
    red[threadIdx.x] = (i < N) ? deg[i] : 0;
    __syncthreads();
    for (int off = SCAN_B / 2; off > 0; off >>= 1) {
        if (threadIdx.x < off) red[threadIdx.x] += red[threadIdx.x + off];
        __syncthreads();
    }
    if (threadIdx.x == 0) bsums[blockIdx.x] = red[0];
}

__global__ __launch_bounds__(SCAN_B) void scan_p2(int* __restrict__ bsums, int B) {
    __shared__ int part[SCAN_B];
    int t = threadIdx.x;
    part[t] = (t < B) ? bsums[t] : 0;
    __syncthreads();
    for (int off = 1; off < SCAN_B; off <<= 1) {
        int v = (t >= off) ? part[t - off] : 0;
        __syncthreads();
        part[t] += v;
        __syncthreads();
    }
    if (t < B) bsums[t] = (t == 0) ? 0 : part[t - 1];   // exclusive
}

__global__ __launch_bounds__(SCAN_B) void scan_p3(const int* __restrict__ deg,
                                                  const int* __restrict__ bsums,
                                                  int* __restrict__ offs,
                                                  int* __restrict__ cursor, int N) {
    __shared__ int part[SCAN_B];
    int t = threadIdx.x;
    int i = blockIdx.x * SCAN_B + t;
    int d = (i < N) ? deg[i] : 0;
    part[t] = d;
    __syncthreads();
    for (int off = 1; off < SCAN_B; off <<= 1) {
        int v = (t >= off) ? part[t - off] : 0;
        __syncthreads();
        part[t] += v;
        __syncthreads();
    }
    int pre = bsums[blockIdx.x] + part[t] - d;
    if (i < N) {
        offs[i] = pre;
        cursor[i] = pre;
        if (i == N - 1) offs[N] = pre + d;
    }
}

__global__ void fill_kernel(const int* __restrict__ rows, const int* __restrict__ cols,
                            const float* __restrict__ ew,
                            const float* __restrict__ Wf1, const float* __restrict__ bf1,
                            const float* __restrict__ wsum, const float* __restrict__ bsum,
                            int* __restrict__ cursor, int2* __restrict__ epack, int E) {
    __shared__ float sW[NFILT], sB[NFILT], sS[NFILT];
    if (threadIdx.x < NFILT) {
        sW[threadIdx.x] = Wf1[threadIdx.x];
        sB[threadIdx.x] = bf1[threadIdx.x];
        sS[threadIdx.x] = wsum[threadIdx.x];
    }
    __syncthreads();
    int e = blockIdx.x * blockDim.x + threadIdx.x;
    if (e >= E) return;
    float f = edge_coeff(ew[e], sW, sB, sS, *bsum);
    int r = rows[e];
    int pos = atomicAdd(&cursor[r], 1);
    epack[pos] = make_int2(cols[e], __float_as_int(f));
}

__global__ __launch_bounds__(256) void gather_kernel(const int* __restrict__ offs,
                                                     const int2* __restrict__ epack,
                                                     const float* __restrict__ x,
                                                     float* __restrict__ agg, int N) {
    int t = threadIdx.x;
    int node = blockIdx.x * 8 + (t >> 5);
    if (node >= N) return;
    int lane = t & 31;
    int s = offs[node], eend = offs[node + 1];
    float4 acc = make_float4(0.f, 0.f, 0.f, 0.f);
    for (int i = s; i < eend; ++i) {
        int2 p = epack[i];
        float f = __int_as_float(p.y);
        const float4 xv = *(const float4*)&x[(size_t)p.x * HIDDEN + lane * 4];
        acc.x = fmaf(xv.x, f, acc.x);
        acc.y = fmaf(xv.y, f, acc.y);
        acc.z = fmaf(xv.z, f, acc.z);
        acc.w = fmaf(xv.w, f, acc.w);
    }
    *(float4*)&agg[(size_t)node * HIDDEN + lane * 4] = acc;
}

// ---------------------------------------------------------------------------
// MFMA MLP, in-place on io=[N,128] fp32:
//   out = scf * (softplus(io @ Wi1 + bi1) @ Wi2) + shf    (BN pre-folded)
// 64 rows/block, 4 waves x 16 rows x 128 cols. bf16 inputs, fp32 accum.
// A-frag: A[m=lane&15][k=quad*8+j]; B-frag from WT[n][k] (contiguous k);
// D: row=quad*4+r, col=lane&15. h round-trips through padded bf16 LDS tile.
// ---------------------------------------------------------------------------
#define HROW 136   // 128 + 8 shorts pad -> 68-dword row stride (2-way max aliasing)

__global__ __launch_bounds__(256) void mlp_mfma_kernel(
    float* io,
    const short* __restrict__ W1T, const short* __restrict__ W2T,
    const float* __restrict__ bi1,
    const float* __restrict__ scf, const float* __restrict__ shf,
    int N) {
    __shared__ short hS[64 * HROW];   // 17 KB

    const int t = threadIdx.x;
    const int wave = t >> 6;
    const int lane = t & 63;
    const int quad = lane >> 4;       // 0..3
    const int m16  = lane & 15;
    const int row0 = blockIdx.x * 64 + wave * 16;   // this wave's 16 rows
    const int arow = row0 + m16;                    // A-row this lane loads

    f32x4 acc[8];
    #pragma unroll
    for (int ct = 0; ct < 8; ++ct) acc[ct] = (f32x4)(0.f);

    // ---- phase A: acc = bf16(A) @ W1
    #pragma unroll
    for (int ks = 0; ks < 4; ++ks) {
        bf16x8 a;
        if (arow < N) {
            const float* ap = &io[(size_t)arow * HIDDEN + ks * 32 + quad * 8];
            float4 v0 = *(const float4*)ap;
            float4 v1 = *(const float4*)(ap + 4);
            a[0] = f2bf(v0.x); a[1] = f2bf(v0.y); a[2] = f2bf(v0.z); a[3] = f2bf(v0.w);
            a[4] = f2bf(v1.x); a[5] = f2bf(v1.y); a[6] = f2bf(v1.z); a[7] = f2bf(v1.w);
        } else {
            #pragma unroll
            for (int j = 0; j < 8; ++j) a[j] = 0;
        }
        #pragma unroll
        for (int ct = 0; ct < 8; ++ct) {
            bf16x8 b = *(const bf16x8*)&W1T[(ct * 16 + m16) * HIDDEN + ks * 32 + quad * 8];
            acc[ct] = __builtin_amdgcn_mfma_f32_16x16x32_bf16(a, b, acc[ct], 0, 0, 0);
        }
    }

    // epilogue A: +bi1, softplus, bf16 -> LDS (A-layout source for phase B)
    #pragma unroll
    for (int ct = 0; ct < 8; ++ct) {
        int col = ct * 16 + m16;
        float b1 = bi1[col];
        #pragma unroll
        for (int r = 0; r < 4; ++r) {
            int lrow = wave * 16 + quad * 4 + r;
            float v = acc[ct][r] + b1;
            float h = (v > 20.f) ? v : log1pf(__expf(v));
            hS[lrow * HROW + col] = f2bf(h);
            acc[ct][r] = 0.f;
        }
    }
    __syncthreads();

    // ---- phase B: acc = h @ W2
    #pragma unroll
    for (int ks = 0; ks < 4; ++ks) {
        bf16x8 a = *(const bf16x8*)&hS[(wave * 16 + m16) * HROW + ks * 32 + quad * 8];
        #pragma unroll
        for (int ct = 0; ct < 8; ++ct) {
            bf16x8 b = *(const bf16x8*)&W2T[(ct * 16 + m16) * HIDDEN + ks * 32 + quad * 8];
            acc[ct] = __builtin_amdgcn_mfma_f32_16x16x32_bf16(a, b, acc[ct], 0, 0, 0);
        }
    }

    // epilogue B: BN (folded) + store
    #pragma unroll
    for (int ct = 0; ct < 8; ++ct) {
        int col = ct * 16 + m16;
        float sc = scf[col], sh = shf[col];
        #pragma unroll
        for (int r = 0; r < 4; ++r) {
            int grow = row0 + quad * 4 + r;
            if (grow < N)
                io[(size_t)grow * HIDDEN + col] = fmaf(acc[ct][r], sc, sh);
        }
    }
}

// ---------------------------------------------------------------------------
// Fallback path kernels (small ws): atomic scatter + fp32 vector MLP
// ---------------------------------------------------------------------------
__global__ void edge_filter_kernel(const float* __restrict__ ew,
                                   const float* __restrict__ Wf1, const float* __restrict__ bf1,
                                   const float* __restrict__ wsum, const float* __restrict__ bsum,
                                   float* __restrict__ fs, int E) {
    __shared__ float sW[NFILT], sB[NFILT], sS[NFILT];
    if (threadIdx.x < NFILT) {
        sW[threadIdx.x] = Wf1[threadIdx.x];
        sB[threadIdx.x] = bf1[threadIdx.x];
        sS[threadIdx.x] = wsum[threadIdx.x];
    }
    __syncthreads();
    int e = blockIdx.x * blockDim.x + threadIdx.x;
    if (e >= E) return;
    fs[e] = edge_coeff(ew[e], sW, sB, sS, *bsum);
}

__global__ void scatter_kernel(const int* __restrict__ rows, const int* __restrict__ cols,
                               const float* __restrict__ x, const float* __restrict__ fs,
                               float* __restrict__ agg, int E) {
    int t = threadIdx.x;
    int e = blockIdx.x * 8 + (t >> 5);
    if (e >= E) return;
    int lane = t & 31;
    int r = rows[e];
    int c = cols[e];
    float f = fs[e];
    const float4 xv = *(const float4*)&x[c * HIDDEN + lane * 4];
    float* dst = &agg[r * HIDDEN + lane * 4];
    atomicAdd(dst + 0, xv.x * f);
    atomicAdd(dst + 1, xv.y * f);
    atomicAdd(dst + 2, xv.z * f);
    atomicAdd(dst + 3, xv.w * f);
}

__global__ __launch_bounds__(256) void mlp_kernel(
    float* __restrict__ io,
    const float* __restrict__ Wi1, const float* __restrict__ bi1,
    const float* __restrict__ Wi2, const float* __restrict__ bi2,
    const float* __restrict__ gamma, const float* __restrict__ beta,
    const float* __restrict__ mean, const float* __restrict__ var,
    int N) {
    __shared__ float As[64 * HIDDEN];
    __shared__ float Wh[64 * HIDDEN];

    const int t = threadIdx.x;
    const int row0 = blockIdx.x * 64;
    const int col4 = (t & 31) * 4;
    const int rgrp = t >> 5;

    #pragma unroll
    for (int i = 0; i < 8; ++i) {
        int f4 = t + 256 * i;
        int r = f4 >> 5, c4 = (f4 & 31) * 4;
        int node = row0 + r;
        float4 v = make_float4(0.f, 0.f, 0.f, 0.f);
        if (node < N) v = *(const float4*)&io[node * HIDDEN + c4];
        *(float4*)&As[r * HIDDEN + c4] = v;
    }

    float acc[8][4];
    #pragma unroll
    for (int r = 0; r < 8; ++r)
        for (int j = 0; j < 4; ++j) acc[r][j] = 0.f;

    for (int kh = 0; kh < 2; ++kh) {
        __syncthreads();
        #pragma unroll
        for (int i = 0; i < 8; ++i) {
            int f4 = t + 256 * i;
            int kr = f4 >> 5, c4 = (f4 & 31) * 4;
            *(float4*)&Wh[kr * HIDDEN + c4] = *(const float4*)&Wi1[(kh * 64 + kr) * HIDDEN + c4];
        }
        __syncthreads();
        for (int k = 0; k < 64; ++k) {
            float4 w = *(const float4*)&Wh[k * HIDDEN + col4];
            #pragma unroll
            for (int r = 0; r < 8; ++r) {
                float a = As[(rgrp + 8 * r) * HIDDEN + kh * 64 + k];
                acc[r][0] = fmaf(a, w.x, acc[r][0]);
                acc[r][1] = fmaf(a, w.y, acc[r][1]);
                acc[r][2] = fmaf(a, w.z, acc[r][2]);
                acc[r][3] = fmaf(a, w.w, acc[r][3]);
            }
        }
    }
    __syncthreads();

    {
        float4 b = *(const float4*)&bi1[col4];
        float bv[4] = {b.x, b.y, b.z, b.w};
        #pragma unroll
        for (int r = 0; r < 8; ++r) {
            float hv[4];
            #pragma unroll
            for (int j = 0; j < 4; ++j) {
                float v = acc[r][j] + bv[j];
                hv[j] = (v > 20.f) ? v : log1pf(__expf(v));
                acc[r][j] = 0.f;
            }
            *(float4*)&As[(rgrp + 8 * r) * HIDDEN + col4] =
                make_float4(hv[0], hv[1], hv[2], hv[3]);
        }
    }

    for (int kh = 0; kh < 2; ++kh) {
        __syncthreads();
        #pragma unroll
        for (int i = 0; i < 8; ++i) {
            int f4 = t + 256 * i;
            int kr = f4 >> 5, c4 = (f4 & 31) * 4;
            *(float4*)&Wh[kr * HIDDEN + c4] = *(const float4*)&Wi2[(kh * 64 + kr) * HIDDEN + c4];
        }
        __syncthreads();
        for (int k = 0; k < 64; ++k) {
            float4 w = *(const float4*)&Wh[k * HIDDEN + col4];
            #pragma unroll
            for (int r = 0; r < 8; ++r) {
                float a = As[(rgrp + 8 * r) * HIDDEN + kh * 64 + k];
                acc[r][0] = fmaf(a, w.x, acc[r][0]);
                acc[r][1] = fmaf(a, w.y, acc[r][1]);
                acc[r][2] = fmaf(a, w.z, acc[r][2]);
                acc[r][3] = fmaf(a, w.w, acc[r][3]);
            }
        }
    }

    {
        float4 b2 = *(const float4*)&bi2[col4];
        float4 g  = *(const float4*)&gamma[col4];
        float4 be = *(const float4*)&beta[col4];
        float4 mu = *(const float4*)&mean[col4];
        float4 va = *(const float4*)&var[col4];
        float bv[4]  = {b2.x, b2.y, b2.z, b2.w};
        float gv[4]  = {g.x, g.y, g.z, g.w};
        float bev[4] = {be.x, be.y, be.z, be.w};
        float muv[4] = {mu.x, mu.y, mu.z, mu.w};
        float vav[4] = {va.x, va.y, va.z, va.w};
        float sc[4];
        #pragma unroll
        for (int j = 0; j < 4; ++j) sc[j] = gv[j] * rsqrtf(vav[j] + 1e-3f);
        #pragma unroll
        for (int r = 0; r < 8; ++r) {
            int node = row0 + rgrp + 8 * r;
            if (node < N) {
                float o[4];
                #pragma unroll
                for (int j = 0; j < 4; ++j)
                    o[j] = (acc[r][j] + bv[j] - muv[j]) * sc[j] + bev[j];
                *(float4*)&io[node * HIDDEN + col4] = make_float4(o[0], o[1], o[2], o[3]);
            }
        }
    }
}

extern "C" void kernel_launch(void* const* d_in, const int* in_sizes, int n_in,
                              void* d_out, int out_size, void* d_ws, size_t ws_size,
                              hipStream_t stream) {
    const float* x    = (const float*)d_in[0];
    const int*   ei   = (const int*)d_in[1];
    const float* ew   = (const float*)d_in[2];
    // d_in[3] = edge_attr: unused by the reference math
    const float* Wf1  = (const float*)d_in[4];
    const float* bf1  = (const float*)d_in[5];
    const float* Wf2  = (const float*)d_in[6];
    const float* bf2  = (const float*)d_in[7];
    const float* Wi1  = (const float*)d_in[8];
    const float* bi1  = (const float*)d_in[9];
    const float* Wi2  = (const float*)d_in[10];
    const float* bi2  = (const float*)d_in[11];
    const float* gam  = (const float*)d_in[12];
    const float* bet  = (const float*)d_in[13];
    const float* mmu  = (const float*)d_in[14];
    const float* mva  = (const float*)d_in[15];

    const int N = in_sizes[0] / HIDDEN;
    const int E = in_sizes[2];
    const int* rows = ei;
    const int* cols = ei + E;

    float* agg = (float*)d_out;    // agg lives in d_out; MLP runs in-place

    const int B = (N + SCAN_B - 1) / SCAN_B;

    // ws layout (CSR path):
    //   deg[N] | offs[N+1] | cursor[N] | bsums[B] | wsum[64] | bsum[1] | pad |
    //   epack[E] (int2) | W1T[16384] bf16 | W2T[16384] bf16 | scf[128] | shf[128]
    char* ws = (char*)d_ws;
    int*   deg    = (int*)ws;
    int*   offs   = deg + N;
    int*   cursor = offs + N + 1;
    int*   bsums  = cursor + N;
    float* wsumv  = (float*)(bsums + B);
    float* bsumv  = wsumv + NFILT;
    size_t epack_off = (((size_t)(3 * N + 1 + B + NFILT + 1) * 4) + 15) & ~(size_t)15;
    int2*  epack  = (int2*)(ws + epack_off);
    size_t wT_off = (epack_off + (size_t)E * sizeof(int2) + 15) & ~(size_t)15;
    short* W1T    = (short*)(ws + wT_off);
    short* W2T    = W1T + HIDDEN * HIDDEN;
    float* scf    = (float*)(W2T + HIDDEN * HIDDEN);
    float* shf    = scf + HIDDEN;
    size_t need   = wT_off + 2 * HIDDEN * HIDDEN * sizeof(short) + 2 * HIDDEN * sizeof(float);

    if (ws_size >= need && B <= SCAN_B) {
        // ---- CSR + MFMA path ----
        hipMemsetAsync(deg, 0, (size_t)N * sizeof(int), stream);
        wsum_kernel<<<1, 64, 0, stream>>>(Wf2, bf2, wsumv, bsumv);
        prep_w_kernel<<<128, 256, 0, stream>>>(Wi1, Wi2, W1T, W2T);
        prep_bn_kernel<<<1, HIDDEN, 0, stream>>>(bi2, gam, bet, mmu, mva, scf, shf);
        count_kernel<<<(E + 255) / 256, 256, 0, stream>>>(rows, deg, E);
        scan_p1<<<B, SCAN_B, 0, stream>>>(deg, bsums, N);
        scan_p2<<<1, SCAN_B, 0, stream>>>(bsums, B);
        scan_p3<<<B, SCAN_B, 0, stream>>>(deg, bsums, offs, cursor, N);
        fill_kernel<<<(E + 255) / 256, 256, 0, stream>>>(rows, cols, ew, Wf1, bf1,
                                                         wsumv, bsumv, cursor, epack, E);
        gather_kernel<<<(N + 7) / 8, 256, 0, stream>>>(offs, epack, x, agg, N);
        mlp_mfma_kernel<<<(N + 63) / 64, 256, 0, stream>>>(agg, W1T, W2T, bi1, scf, shf, N);
    } else {
        // ---- fallback: atomic scatter + fp32 MLP ----
        float* fs = (float*)d_ws;             // [E]
        float* w2 = fs + E;                   // [64]
        float* b2 = w2 + NFILT;               // [1]
        hipMemsetAsync(d_out, 0, (size_t)out_size * sizeof(float), stream);
        wsum_kernel<<<1, 64, 0, stream>>>(Wf2, bf2, w2, b2);
        edge_filter_kernel<<<(E + 255) / 256, 256, 0, stream>>>(ew, Wf1, bf1, w2, b2, fs, E);
        scatter_kernel<<<(E + 7) / 8, 256, 0, stream>>>(rows, cols, x, fs, agg, E);
        mlp_kernel<<<(N + 63) / 64, 256, 0, stream>>>(agg, Wi1, bi1, Wi2, bi2,
                                                      gam, bet, mmu, mva, N);
    }
}

// Round 5
// 460.531 us; speedup vs baseline: 6.4882x; 1.1350x over previous
//
#include <hip/hip_runtime.h>
#include <math.h>

#define HIDDEN 128
#define NFILT 64
#define SCAN_B 1024
#define LUTK 2048   // LUT entries over w in [0,8]; lerp err ~5e-7

typedef __attribute__((ext_vector_type(8))) short bf16x8;
typedef __attribute__((ext_vector_type(4))) float f32x4;

__device__ __forceinline__ short f2bf(float f) {
    unsigned u = __float_as_uint(f);
    unsigned r = (u + 0x7fffu + ((u >> 16) & 1u)) >> 16;   // RNE
    return (short)r;
}

// ---------------------------------------------------------------------------
// wsum[j] = sum_f Wf2[j][f]; bsum = sum_f bf2[f]
// ---------------------------------------------------------------------------
__global__ void wsum_kernel(const float* __restrict__ Wf2, const float* __restrict__ bf2,
                            float* __restrict__ wsum, float* __restrict__ bsum) {
    int j = threadIdx.x;  // 0..63
    float s = 0.f;
    for (int f = 0; f < NFILT; ++f) s += Wf2[j * NFILT + f];
    wsum[j] = s;
    if (j == 0) {
        float b = 0.f;
        for (int f = 0; f < NFILT; ++f) b += bf2[f];
        *bsum = b;
    }
}

__device__ __forceinline__ float edge_coeff(float w,
                                            const float* sW, const float* sB,
                                            const float* sS, float bsum) {
    float s = fmaf(w, 0.25f, -1.0f);          // w * (2/8) - 1
    float acc = bsum;
    #pragma unroll 8
    for (int j = 0; j < NFILT; ++j)
        acc += tanhf(fmaf(s, sW[j], sB[j])) * sS[j];
    float cut = (w <= 8.0f) ? 0.5f * (cosf(w * 0.39269908169872414f) + 1.0f) : 0.0f;
    return acc * cut;
}

// LUT over the scalar filter function g(w), w in [0,8], LUTK+1 samples
__global__ void lut_kernel(const float* __restrict__ Wf1, const float* __restrict__ bf1,
                           const float* __restrict__ wsum, const float* __restrict__ bsum,
                           float* __restrict__ lut) {
    int i = blockIdx.x * 256 + threadIdx.x;
    if (i > LUTK) return;
    float w = 8.0f * (float)i / (float)LUTK;
    lut[i] = edge_coeff(w, Wf1, bf1, wsum, *bsum);
}

__device__ __forceinline__ float lut_eval(const float* sl, float w) {
    float t = w * ((float)LUTK / 8.0f);
    t = fminf(fmaxf(t, 0.f), (float)LUTK);
    int i = (int)t;
    i = min(i, LUTK - 1);
    return fmaf(t - (float)i, sl[i + 1] - sl[i], sl[i]);
}

// ---------------------------------------------------------------------------
// Prep: W1T/W2T = bf16 transpose of Wi1/Wi2; BN folded into scale/shift
// ---------------------------------------------------------------------------
__global__ void prep_w_kernel(const float* __restrict__ Wi1, const float* __restrict__ Wi2,
                              short* __restrict__ W1T, short* __restrict__ W2T) {
    int idx = blockIdx.x * 256 + threadIdx.x;   // 0..32767
    const float* src = (idx < 16384) ? Wi1 : Wi2;
    short* dst = (idx < 16384) ? W1T : W2T;
    int i = idx & 16383;
    int k = i >> 7, n = i & 127;
    dst[n * HIDDEN + k] = f2bf(src[i]);
}

__global__ void prep_bn_kernel(const float* __restrict__ bi2,
                               const float* __restrict__ gamma, const float* __restrict__ beta,
                               const float* __restrict__ mean, const float* __restrict__ var,
                               float* __restrict__ scf, float* __restrict__ shf) {
    int j = threadIdx.x;  // 0..127
    float sc = gamma[j] * rsqrtf(var[j] + 1e-3f);
    scf[j] = sc;
    shf[j] = (bi2[j] - mean[j]) * sc + beta[j];
}

// ---------------------------------------------------------------------------
// CSR build
// ---------------------------------------------------------------------------
// rank path: remember each edge's arrival rank within its row
__global__ void count_rank_kernel(const int* __restrict__ rows, int* __restrict__ deg,
                                  int* __restrict__ rank, int E) {
    int e = blockIdx.x * blockDim.x + threadIdx.x;
    if (e < E) rank[e] = atomicAdd(&deg[rows[e]], 1);
}

// cursor path: plain histogram
__global__ void count_kernel(const int* __restrict__ rows, int* __restrict__ deg, int E) {
    int e = blockIdx.x * blockDim.x + threadIdx.x;
    if (e < E) atomicAdd(&deg[rows[e]], 1);
}

__global__ __launch_bounds__(SCAN_B) void scan_p1(const int* __restrict__ deg,
                                                  int* __restrict__ bsums, int N) {
    __shared__ int red[SCAN_B];
    int i = blockIdx.x * SCAN_B + threadIdx.x;
    red[threadIdx.x] = (i < N) ? deg[i] : 0;
    __syncthreads();
    for (int off = SCAN_B / 2; off > 0; off >>= 1) {
        if (threadIdx.x < off) red[threadIdx.x] += red[threadIdx.x + off];
        __syncthreads();
    }
    if (threadIdx.x == 0) bsums[blockIdx.x] = red[0];
}

__global__ __launch_bounds__(SCAN_B) void scan_p2(int* __restrict__ bsums, int B) {
    __shared__ int part[SCAN_B];
    int t = threadIdx.x;
    part[t] = (t < B) ? bsums[t] : 0;
    __syncthreads();
    for (int off = 1; off < SCAN_B; off <<= 1) {
        int v = (t >= off) ? part[t - off] : 0;
        __syncthreads();
        part[t] += v;
        __syncthreads();
    }
    if (t < B) bsums[t] = (t == 0) ? 0 : part[t - 1];   // exclusive
}

// scan_p3: writes offs; optionally rewrites deg in-place as cursor (cursor path)
template <bool WRITE_CURSOR>
__global__ __launch_bounds__(SCAN_B) void scan_p3_t(int* __restrict__ deg,
                                                    const int* __restrict__ bsums,
                                                    int* __restrict__ offs, int N) {
    __shared__ int part[SCAN_B];
    int t = threadIdx.x;
    int i = blockIdx.x * SCAN_B + t;
    int d = (i < N) ? deg[i] : 0;
    part[t] = d;
    __syncthreads();
    for (int off = 1; off < SCAN_B; off <<= 1) {
        int v = (t >= off) ? part[t - off] : 0;
        __syncthreads();
        part[t] += v;
        __syncthreads();
    }
    int pre = bsums[blockIdx.x] + part[t] - d;
    if (i < N) {
        offs[i] = pre;
        if (WRITE_CURSOR) deg[i] = pre;   // deg becomes cursor
        if (i == N - 1) offs[N] = pre + d;
    }
}

// fill (rank path): no atomics — pos = offs[row] + rank
__global__ __launch_bounds__(256) void fill_rank_kernel(
    const int* __restrict__ rows, const int* __restrict__ cols,
    const float* __restrict__ ew, const int* __restrict__ rank,
    const int* __restrict__ offs, const float* __restrict__ lut,
    int2* __restrict__ epack, int E) {
    __shared__ float sl[LUTK + 1];
    for (int i = threadIdx.x; i <= LUTK; i += 256) sl[i] = lut[i];
    __syncthreads();
    int e = blockIdx.x * 256 + threadIdx.x;
    if (e >= E) return;
    float f = lut_eval(sl, ew[e]);
    int pos = offs[rows[e]] + rank[e];
    epack[pos] = make_int2(cols[e], __float_as_int(f));
}

// fill (cursor path): cursor atomic (cursor aliases deg, rewritten by scan_p3)
__global__ __launch_bounds__(256) void fill_cursor_kernel(
    const int* __restrict__ rows, const int* __restrict__ cols,
    const float* __restrict__ ew, int* __restrict__ cursor,
    const float* __restrict__ lut, int2* __restrict__ epack, int E) {
    __shared__ float sl[LUTK + 1];
    for (int i = threadIdx.x; i <= LUTK; i += 256) sl[i] = lut[i];
    __syncthreads();
    int e = blockIdx.x * 256 + threadIdx.x;
    if (e >= E) return;
    float f = lut_eval(sl, ew[e]);
    int pos = atomicAdd(&cursor[rows[e]], 1);
    epack[pos] = make_int2(cols[e], __float_as_int(f));
}

// gather: 32 lanes per node; acc[node][:] = sum over its edges x[col]*f
__global__ __launch_bounds__(256) void gather_kernel(const int* __restrict__ offs,
                                                     const int2* __restrict__ epack,
                                                     const float* __restrict__ x,
                                                     float* __restrict__ agg, int N) {
    int t = threadIdx.x;
    int node = blockIdx.x * 8 + (t >> 5);
    if (node >= N) return;
    int lane = t & 31;
    int s = offs[node], eend = offs[node + 1];
    float4 acc = make_float4(0.f, 0.f, 0.f, 0.f);
    for (int i = s; i < eend; ++i) {
        int2 p = epack[i];
        float f = __int_as_float(p.y);
        const float4 xv = *(const float4*)&x[(size_t)p.x * HIDDEN + lane * 4];
        acc.x = fmaf(xv.x, f, acc.x);
        acc.y = fmaf(xv.y, f, acc.y);
        acc.z = fmaf(xv.z, f, acc.z);
        acc.w = fmaf(xv.w, f, acc.w);
    }
    *(float4*)&agg[(size_t)node * HIDDEN + lane * 4] = acc;
}

// ---------------------------------------------------------------------------
// MFMA MLP, in-place on io=[N,128] fp32 (unchanged from round 4)
// ---------------------------------------------------------------------------
#define HROW 136   // 128 + 8 shorts pad -> 68-dword row stride (2-way max aliasing)

__global__ __launch_bounds__(256) void mlp_mfma_kernel(
    float* io,
    const short* __restrict__ W1T, const short* __restrict__ W2T,
    const float* __restrict__ bi1,
    const float* __restrict__ scf, const float* __restrict__ shf,
    int N) {
    __shared__ short hS[64 * HROW];   // 17 KB

    const int t = threadIdx.x;
    const int wave = t >> 6;
    const int lane = t & 63;
    const int quad = lane >> 4;       // 0..3
    const int m16  = lane & 15;
    const int row0 = blockIdx.x * 64 + wave * 16;
    const int arow = row0 + m16;

    f32x4 acc[8];
    #pragma unroll
    for (int ct = 0; ct < 8; ++ct) acc[ct] = (f32x4)(0.f);

    // ---- phase A: acc = bf16(A) @ W1
    #pragma unroll
    for (int ks = 0; ks < 4; ++ks) {
        bf16x8 a;
        if (arow < N) {
            const float* ap = &io[(size_t)arow * HIDDEN + ks * 32 + quad * 8];
            float4 v0 = *(const float4*)ap;
            float4 v1 = *(const float4*)(ap + 4);
            a[0] = f2bf(v0.x); a[1] = f2bf(v0.y); a[2] = f2bf(v0.z); a[3] = f2bf(v0.w);
            a[4] = f2bf(v1.x); a[5] = f2bf(v1.y); a[6] = f2bf(v1.z); a[7] = f2bf(v1.w);
        } else {
            #pragma unroll
            for (int j = 0; j < 8; ++j) a[j] = 0;
        }
        #pragma unroll
        for (int ct = 0; ct < 8; ++ct) {
            bf16x8 b = *(const bf16x8*)&W1T[(ct * 16 + m16) * HIDDEN + ks * 32 + quad * 8];
            acc[ct] = __builtin_amdgcn_mfma_f32_16x16x32_bf16(a, b, acc[ct], 0, 0, 0);
        }
    }

    // epilogue A: +bi1, softplus, bf16 -> LDS
    #pragma unroll
    for (int ct = 0; ct < 8; ++ct) {
        int col = ct * 16 + m16;
        float b1 = bi1[col];
        #pragma unroll
        for (int r = 0; r < 4; ++r) {
            int lrow = wave * 16 + quad * 4 + r;
            float v = acc[ct][r] + b1;
            float h = (v > 20.f) ? v : log1pf(__expf(v));
            hS[lrow * HROW + col] = f2bf(h);
            acc[ct][r] = 0.f;
        }
    }
    __syncthreads();

    // ---- phase B: acc = h @ W2
    #pragma unroll
    for (int ks = 0; ks < 4; ++ks) {
        bf16x8 a = *(const bf16x8*)&hS[(wave * 16 + m16) * HROW + ks * 32 + quad * 8];
        #pragma unroll
        for (int ct = 0; ct < 8; ++ct) {
            bf16x8 b = *(const bf16x8*)&W2T[(ct * 16 + m16) * HIDDEN + ks * 32 + quad * 8];
            acc[ct] = __builtin_amdgcn_mfma_f32_16x16x32_bf16(a, b, acc[ct], 0, 0, 0);
        }
    }

    // epilogue B: BN (folded) + store
    #pragma unroll
    for (int ct = 0; ct < 8; ++ct) {
        int col = ct * 16 + m16;
        float sc = scf[col], sh = shf[col];
        #pragma unroll
        for (int r = 0; r < 4; ++r) {
            int grow = row0 + quad * 4 + r;
            if (grow < N)
                io[(size_t)grow * HIDDEN + col] = fmaf(acc[ct][r], sc, sh);
        }
    }
}

// ---------------------------------------------------------------------------
// Fallback path kernels (tiny ws): atomic scatter + fp32 vector MLP
// ---------------------------------------------------------------------------
__global__ void edge_filter_kernel(const float* __restrict__ ew,
                                   const float* __restrict__ Wf1, const float* __restrict__ bf1,
                                   const float* __restrict__ wsum, const float* __restrict__ bsum,
                                   float* __restrict__ fs, int E) {
    __shared__ float sW[NFILT], sB[NFILT], sS[NFILT];
    if (threadIdx.x < NFILT) {
        sW[threadIdx.x] = Wf1[threadIdx.x];
        sB[threadIdx.x] = bf1[threadIdx.x];
        sS[threadIdx.x] = wsum[threadIdx.x];
    }
    __syncthreads();
    int e = blockIdx.x * blockDim.x + threadIdx.x;
    if (e >= E) return;
    fs[e] = edge_coeff(ew[e], sW, sB, sS, *bsum);
}

__global__ void scatter_kernel(const int* __restrict__ rows, const int* __restrict__ cols,
                               const float* __restrict__ x, const float* __restrict__ fs,
                               float* __restrict__ agg, int E) {
    int t = threadIdx.x;
    int e = blockIdx.x * 8 + (t >> 5);
    if (e >= E) return;
    int lane = t & 31;
    int r = rows[e];
    int c = cols[e];
    float f = fs[e];
    const float4 xv = *(const float4*)&x[c * HIDDEN + lane * 4];
    float* dst = &agg[r * HIDDEN + lane * 4];
    atomicAdd(dst + 0, xv.x * f);
    atomicAdd(dst + 1, xv.y * f);
    atomicAdd(dst + 2, xv.z * f);
    atomicAdd(dst + 3, xv.w * f);
}

__global__ __launch_bounds__(256) void mlp_kernel(
    float* __restrict__ io,
    const float* __restrict__ Wi1, const float* __restrict__ bi1,
    const float* __restrict__ Wi2, const float* __restrict__ bi2,
    const float* __restrict__ gamma, const float* __restrict__ beta,
    const float* __restrict__ mean, const float* __restrict__ var,
    int N) {
    __shared__ float As[64 * HIDDEN];
    __shared__ float Wh[64 * HIDDEN];

    const int t = threadIdx.x;
    const int row0 = blockIdx.x * 64;
    const int col4 = (t & 31) * 4;
    const int rgrp = t >> 5;

    #pragma unroll
    for (int i = 0; i < 8; ++i) {
        int f4 = t + 256 * i;
        int r = f4 >> 5, c4 = (f4 & 31) * 4;
        int node = row0 + r;
        float4 v = make_float4(0.f, 0.f, 0.f, 0.f);
        if (node < N) v = *(const float4*)&io[node * HIDDEN + c4];
        *(float4*)&As[r * HIDDEN + c4] = v;
    }

    float acc[8][4];
    #pragma unroll
    for (int r = 0; r < 8; ++r)
        for (int j = 0; j < 4; ++j) acc[r][j] = 0.f;

    for (int kh = 0; kh < 2; ++kh) {
        __syncthreads();
        #pragma unroll
        for (int i = 0; i < 8; ++i) {
            int f4 = t + 256 * i;
            int kr = f4 >> 5, c4 = (f4 & 31) * 4;
            *(float4*)&Wh[kr * HIDDEN + c4] = *(const float4*)&Wi1[(kh * 64 + kr) * HIDDEN + c4];
        }
        __syncthreads();
        for (int k = 0; k < 64; ++k) {
            float4 w = *(const float4*)&Wh[k * HIDDEN + col4];
            #pragma unroll
            for (int r = 0; r < 8; ++r) {
                float a = As[(rgrp + 8 * r) * HIDDEN + kh * 64 + k];
                acc[r][0] = fmaf(a, w.x, acc[r][0]);
                acc[r][1] = fmaf(a, w.y, acc[r][1]);
                acc[r][2] = fmaf(a, w.z, acc[r][2]);
                acc[r][3] = fmaf(a, w.w, acc[r][3]);
            }
        }
    }
    __syncthreads();

    {
        float4 b = *(const float4*)&bi1[col4];
        float bv[4] = {b.x, b.y, b.z, b.w};
        #pragma unroll
        for (int r = 0; r < 8; ++r) {
            float hv[4];
            #pragma unroll
            for (int j = 0; j < 4; ++j) {
                float v = acc[r][j] + bv[j];
                hv[j] = (v > 20.f) ? v : log1pf(__expf(v));
                acc[r][j] = 0.f;
            }
            *(float4*)&As[(rgrp + 8 * r) * HIDDEN + col4] =
                make_float4(hv[0], hv[1], hv[2], hv[3]);
        }
    }

    for (int kh = 0; kh < 2; ++kh) {
        __syncthreads();
        #pragma unroll
        for (int i = 0; i < 8; ++i) {
            int f4 = t + 256 * i;
            int kr = f4 >> 5, c4 = (f4 & 31) * 4;
            *(float4*)&Wh[kr * HIDDEN + c4] = *(const float4*)&Wi2[(kh * 64 + kr) * HIDDEN + c4];
        }
        __syncthreads();
        for (int k = 0; k < 64; ++k) {
            float4 w = *(const float4*)&Wh[k * HIDDEN + col4];
            #pragma unroll
            for (int r = 0; r < 8; ++r) {
                float a = As[(rgrp + 8 * r) * HIDDEN + kh * 64 + k];
                acc[r][0] = fmaf(a, w.x, acc[r][0]);
                acc[r][1] = fmaf(a, w.y, acc[r][1]);
                acc[r][2] = fmaf(a, w.z, acc[r][2]);
                acc[r][3] = fmaf(a, w.w, acc[r][3]);
            }
        }
    }

    {
        float4 b2 = *(const float4*)&bi2[col4];
        float4 g  = *(const float4*)&gamma[col4];
        float4 be = *(const float4*)&beta[col4];
        float4 mu = *(const float4*)&mean[col4];
        float4 va = *(const float4*)&var[col4];
        float bv[4]  = {b2.x, b2.y, b2.z, b2.w};
        float gv[4]  = {g.x, g.y, g.z, g.w};
        float bev[4] = {be.x, be.y, be.z, be.w};
        float muv[4] = {mu.x, mu.y, mu.z, mu.w};
        float vav[4] = {va.x, va.y, va.z, va.w};
        float sc[4];
        #pragma unroll
        for (int j = 0; j < 4; ++j) sc[j] = gv[j] * rsqrtf(vav[j] + 1e-3f);
        #pragma unroll
        for (int r = 0; r < 8; ++r) {
            int node = row0 + rgrp + 8 * r;
            if (node < N) {
                float o[4];
                #pragma unroll
                for (int j = 0; j < 4; ++j)
                    o[j] = (acc[r][j] + bv[j] - muv[j]) * sc[j] + bev[j];
                *(float4*)&io[node * HIDDEN + col4] = make_float4(o[0], o[1], o[2], o[3]);
            }
        }
    }
}

extern "C" void kernel_launch(void* const* d_in, const int* in_sizes, int n_in,
                              void* d_out, int out_size, void* d_ws, size_t ws_size,
                              hipStream_t stream) {
    const float* x    = (const float*)d_in[0];
    const int*   ei   = (const int*)d_in[1];
    const float* ew   = (const float*)d_in[2];
    // d_in[3] = edge_attr: unused by the reference math
    const float* Wf1  = (const float*)d_in[4];
    const float* bf1  = (const float*)d_in[5];
    const float* Wf2  = (const float*)d_in[6];
    const float* bf2  = (const float*)d_in[7];
    const float* Wi1  = (const float*)d_in[8];
    const float* bi1  = (const float*)d_in[9];
    const float* Wi2  = (const float*)d_in[10];
    const float* bi2  = (const float*)d_in[11];
    const float* gam  = (const float*)d_in[12];
    const float* bet  = (const float*)d_in[13];
    const float* mmu  = (const float*)d_in[14];
    const float* mva  = (const float*)d_in[15];

    const int N = in_sizes[0] / HIDDEN;
    const int E = in_sizes[2];
    const int* rows = ei;
    const int* cols = ei + E;

    float* agg = (float*)d_out;    // agg lives in d_out; MLP runs in-place

    const int B = (N + SCAN_B - 1) / SCAN_B;

    // ws layout:
    //   deg[N] (cursor-path: rewritten as cursor by scan_p3) | offs[N+1] | bsums[B] |
    //   wsum[64] | bsum[1] | lut[LUTK+1] | pad16 | epack[E] int2 | pad16 |
    //   W1T[16384] bf16 | W2T[16384] bf16 | scf[128] | shf[128] | [rank[E] if it fits]
    char* ws = (char*)d_ws;
    int*   deg    = (int*)ws;
    int*   offs   = deg + N;
    int*   bsums  = offs + N + 1;
    float* wsumv  = (float*)(bsums + B);
    float* bsumv  = wsumv + NFILT;
    float* lut    = bsumv + 1;
    size_t hdr_ints  = (size_t)(2 * N + 1 + B + NFILT + 1 + LUTK + 1);
    size_t epack_off = ((hdr_ints * 4) + 15) & ~(size_t)15;
    int2*  epack  = (int2*)(ws + epack_off);
    size_t wT_off = (epack_off + (size_t)E * sizeof(int2) + 15) & ~(size_t)15;
    short* W1T    = (short*)(ws + wT_off);
    short* W2T    = W1T + HIDDEN * HIDDEN;
    float* scf    = (float*)(W2T + HIDDEN * HIDDEN);
    float* shf    = scf + HIDDEN;
    size_t base_need = wT_off + 2 * HIDDEN * HIDDEN * sizeof(short) + 2 * HIDDEN * sizeof(float);
    size_t rank_off  = (base_need + 15) & ~(size_t)15;
    int*   rank   = (int*)(ws + rank_off);
    size_t rank_need = rank_off + (size_t)E * sizeof(int);

    if (ws_size >= base_need && B <= SCAN_B) {
        const bool use_rank = (ws_size >= rank_need);
        hipMemsetAsync(deg, 0, (size_t)N * sizeof(int), stream);
        wsum_kernel<<<1, 64, 0, stream>>>(Wf2, bf2, wsumv, bsumv);
        lut_kernel<<<(LUTK + 256) / 256, 256, 0, stream>>>(Wf1, bf1, wsumv, bsumv, lut);
        prep_w_kernel<<<128, 256, 0, stream>>>(Wi1, Wi2, W1T, W2T);
        prep_bn_kernel<<<1, HIDDEN, 0, stream>>>(bi2, gam, bet, mmu, mva, scf, shf);
        if (use_rank)
            count_rank_kernel<<<(E + 255) / 256, 256, 0, stream>>>(rows, deg, rank, E);
        else
            count_kernel<<<(E + 255) / 256, 256, 0, stream>>>(rows, deg, E);
        scan_p1<<<B, SCAN_B, 0, stream>>>(deg, bsums, N);
        scan_p2<<<1, SCAN_B, 0, stream>>>(bsums, B);
        if (use_rank) {
            scan_p3_t<false><<<B, SCAN_B, 0, stream>>>(deg, bsums, offs, N);
            fill_rank_kernel<<<(E + 255) / 256, 256, 0, stream>>>(rows, cols, ew, rank,
                                                                  offs, lut, epack, E);
        } else {
            scan_p3_t<true><<<B, SCAN_B, 0, stream>>>(deg, bsums, offs, N);
            fill_cursor_kernel<<<(E + 255) / 256, 256, 0, stream>>>(rows, cols, ew, deg,
                                                                    lut, epack, E);
        }
        gather_kernel<<<(N + 7) / 8, 256, 0, stream>>>(offs, epack, x, agg, N);
        mlp_mfma_kernel<<<(N + 63) / 64, 256, 0, stream>>>(agg, W1T, W2T, bi1, scf, shf, N);
    } else {
        // ---- fallback: atomic scatter + fp32 MLP ----
        float* fs = (float*)d_ws;             // [E]
        float* w2 = fs + E;                   // [64]
        float* b2 = w2 + NFILT;               // [1]
        hipMemsetAsync(d_out, 0, (size_t)out_size * sizeof(float), stream);
        wsum_kernel<<<1, 64, 0, stream>>>(Wf2, bf2, w2, b2);
        edge_filter_kernel<<<(E + 255) / 256, 256, 0, stream>>>(ew, Wf1, bf1, w2, b2, fs, E);
        scatter_kernel<<<(E + 7) / 8, 256, 0, stream>>>(rows, cols, x, fs, agg, E);
        mlp_kernel<<<(N + 63) / 64, 256, 0, stream>>>(agg, Wi1, bi1, Wi2, bi2,
                                                      gam, bet, mmu, mva, N);
    }
}

// Round 6
// 453.264 us; speedup vs baseline: 6.5923x; 1.0160x over previous
//
#include <hip/hip_runtime.h>
#include <math.h>

#define HIDDEN 128
#define NFILT 64
#define SCAN_B 1024
#define LUTK 2048   // LUT entries over w in [0,8]; lerp err ~5e-7

typedef __attribute__((ext_vector_type(8))) short bf16x8;
typedef __attribute__((ext_vector_type(4))) float f32x4;

__device__ __forceinline__ short f2bf(float f) {
    unsigned u = __float_as_uint(f);
    unsigned r = (u + 0x7fffu + ((u >> 16) & 1u)) >> 16;   // RNE
    return (short)r;
}
__device__ __forceinline__ float bf2f(unsigned short u) {
    return __uint_as_float(((unsigned)u) << 16);
}

// ---------------------------------------------------------------------------
// wsum[j] = sum_f Wf2[j][f]; bsum = sum_f bf2[f]
// ---------------------------------------------------------------------------
__global__ void wsum_kernel(const float* __restrict__ Wf2, const float* __restrict__ bf2,
                            float* __restrict__ wsum, float* __restrict__ bsum) {
    int j = threadIdx.x;  // 0..63
    float s = 0.f;
    for (int f = 0; f < NFILT; ++f) s += Wf2[j * NFILT + f];
    wsum[j] = s;
    if (j == 0) {
        float b = 0.f;
        for (int f = 0; f < NFILT; ++f) b += bf2[f];
        *bsum = b;
    }
}

__device__ __forceinline__ float edge_coeff(float w,
                                            const float* sW, const float* sB,
                                            const float* sS, float bsum) {
    float s = fmaf(w, 0.25f, -1.0f);          // w * (2/8) - 1
    float acc = bsum;
    #pragma unroll 8
    for (int j = 0; j < NFILT; ++j)
        acc += tanhf(fmaf(s, sW[j], sB[j])) * sS[j];
    float cut = (w <= 8.0f) ? 0.5f * (cosf(w * 0.39269908169872414f) + 1.0f) : 0.0f;
    return acc * cut;
}

// LUT over the scalar filter function g(w), w in [0,8], LUTK+1 samples
__global__ void lut_kernel(const float* __restrict__ Wf1, const float* __restrict__ bf1,
                           const float* __restrict__ wsum, const float* __restrict__ bsum,
                           float* __restrict__ lut) {
    int i = blockIdx.x * 256 + threadIdx.x;
    if (i > LUTK) return;
    float w = 8.0f * (float)i / (float)LUTK;
    lut[i] = edge_coeff(w, Wf1, bf1, wsum, *bsum);
}

__device__ __forceinline__ float lut_eval(const float* sl, float w) {
    float t = w * ((float)LUTK / 8.0f);
    t = fminf(fmaxf(t, 0.f), (float)LUTK);
    int i = (int)t;
    i = min(i, LUTK - 1);
    return fmaf(t - (float)i, sl[i + 1] - sl[i], sl[i]);
}

// ---------------------------------------------------------------------------
// Prep: W1T/W2T = bf16 transpose of Wi1/Wi2; BN folded; x -> bf16
// ---------------------------------------------------------------------------
__global__ void prep_w_kernel(const float* __restrict__ Wi1, const float* __restrict__ Wi2,
                              short* __restrict__ W1T, short* __restrict__ W2T) {
    int idx = blockIdx.x * 256 + threadIdx.x;   // 0..32767
    const float* src = (idx < 16384) ? Wi1 : Wi2;
    short* dst = (idx < 16384) ? W1T : W2T;
    int i = idx & 16383;
    int k = i >> 7, n = i & 127;
    dst[n * HIDDEN + k] = f2bf(src[i]);
}

__global__ void prep_bn_kernel(const float* __restrict__ bi2,
                               const float* __restrict__ gamma, const float* __restrict__ beta,
                               const float* __restrict__ mean, const float* __restrict__ var,
                               float* __restrict__ scf, float* __restrict__ shf) {
    int j = threadIdx.x;  // 0..127
    float sc = gamma[j] * rsqrtf(var[j] + 1e-3f);
    scf[j] = sc;
    shf[j] = (bi2[j] - mean[j]) * sc + beta[j];
}

// x (fp32) -> xh (bf16), 8 elems/thread
__global__ void x2bf_kernel(const float* __restrict__ x, short* __restrict__ xh, int total8) {
    int i = blockIdx.x * 256 + threadIdx.x;
    if (i >= total8) return;
    const float4 v0 = *(const float4*)&x[(size_t)i * 8];
    const float4 v1 = *(const float4*)&x[(size_t)i * 8 + 4];
    bf16x8 o;
    o[0] = f2bf(v0.x); o[1] = f2bf(v0.y); o[2] = f2bf(v0.z); o[3] = f2bf(v0.w);
    o[4] = f2bf(v1.x); o[5] = f2bf(v1.y); o[6] = f2bf(v1.z); o[7] = f2bf(v1.w);
    *(bf16x8*)&xh[(size_t)i * 8] = o;
}

// ---------------------------------------------------------------------------
// CSR build
// ---------------------------------------------------------------------------
__global__ void count_rank_kernel(const int* __restrict__ rows, int* __restrict__ deg,
                                  int* __restrict__ rank, int E) {
    int e = blockIdx.x * blockDim.x + threadIdx.x;
    if (e < E) rank[e] = atomicAdd(&deg[rows[e]], 1);
}

__global__ void count_kernel(const int* __restrict__ rows, int* __restrict__ deg, int E) {
    int e = blockIdx.x * blockDim.x + threadIdx.x;
    if (e < E) atomicAdd(&deg[rows[e]], 1);
}

__global__ __launch_bounds__(SCAN_B) void scan_p1(const int* __restrict__ deg,
                                                  int* __restrict__ bsums, int N) {
    __shared__ int red[SCAN_B];
    int i = blockIdx.x * SCAN_B + threadIdx.x;
    red[threadIdx.x] = (i < N) ? deg[i] : 0;
    __syncthreads();
    for (int off = SCAN_B / 2; off > 0; off >>= 1) {
        if (threadIdx.x < off) red[threadIdx.x] += red[threadIdx.x + off];
        __syncthreads();
    }
    if (threadIdx.x == 0) bsums[blockIdx.x] = red[0];
}

__global__ __launch_bounds__(SCAN_B) void scan_p2(int* __restrict__ bsums, int B) {
    __shared__ int part[SCAN_B];
    int t = threadIdx.x;
    part[t] = (t < B) ? bsums[t] : 0;
    __syncthreads();
    for (int off = 1; off < SCAN_B; off <<= 1) {
        int v = (t >= off) ? part[t - off] : 0;
        __syncthreads();
        part[t] += v;
        __syncthreads();
    }
    if (t < B) bsums[t] = (t == 0) ? 0 : part[t - 1];   // exclusive
}

template <bool WRITE_CURSOR>
__global__ __launch_bounds__(SCAN_B) void scan_p3_t(int* __restrict__ deg,
                                                    const int* __restrict__ bsums,
                                                    int* __restrict__ offs, int N) {
    __shared__ int part[SCAN_B];
    int t = threadIdx.x;
    int i = blockIdx.x * SCAN_B + t;
    int d = (i < N) ? deg[i] : 0;
    part[t] = d;
    __syncthreads();
    for (int off = 1; off < SCAN_B; off <<= 1) {
        int v = (t >= off) ? part[t - off] : 0;
        __syncthreads();
        part[t] += v;
        __syncthreads();
    }
    int pre = bsums[blockIdx.x] + part[t] - d;
    if (i < N) {
        offs[i] = pre;
        if (WRITE_CURSOR) deg[i] = pre;   // deg becomes cursor
        if (i == N - 1) offs[N] = pre + d;
    }
}

// fill (rank path): no atomics — pos = offs[row] + rank
__global__ __launch_bounds__(256) void fill_rank_kernel(
    const int* __restrict__ rows, const int* __restrict__ cols,
    const float* __restrict__ ew, const int* __restrict__ rank,
    const int* __restrict__ offs, const float* __restrict__ lut,
    int2* __restrict__ epack, int E) {
    __shared__ float sl[LUTK + 1];
    for (int i = threadIdx.x; i <= LUTK; i += 256) sl[i] = lut[i];
    __syncthreads();
    int e = blockIdx.x * 256 + threadIdx.x;
    if (e >= E) return;
    float f = lut_eval(sl, ew[e]);
    int pos = offs[rows[e]] + rank[e];
    epack[pos] = make_int2(cols[e], __float_as_int(f));
}

// fill (cursor path)
__global__ __launch_bounds__(256) void fill_cursor_kernel(
    const int* __restrict__ rows, const int* __restrict__ cols,
    const float* __restrict__ ew, int* __restrict__ cursor,
    const float* __restrict__ lut, int2* __restrict__ epack, int E) {
    __shared__ float sl[LUTK + 1];
    for (int i = threadIdx.x; i <= LUTK; i += 256) sl[i] = lut[i];
    __syncthreads();
    int e = blockIdx.x * 256 + threadIdx.x;
    if (e >= E) return;
    float f = lut_eval(sl, ew[e]);
    int pos = atomicAdd(&cursor[rows[e]], 1);
    epack[pos] = make_int2(cols[e], __float_as_int(f));
}

// ---------------------------------------------------------------------------
// gather (bf16 x): 32 lanes/node, ushort4/lane = 256 B per edge row;
// fp32 accumulate, bf16 store to aggh (same rounding MFMA would apply anyway)
// ---------------------------------------------------------------------------
__global__ __launch_bounds__(256) void gather_bf_kernel(const int* __restrict__ offs,
                                                        const int2* __restrict__ epack,
                                                        const short* __restrict__ xh,
                                                        short* __restrict__ aggh, int N) {
    int t = threadIdx.x;
    int node = blockIdx.x * 8 + (t >> 5);
    if (node >= N) return;
    int lane = t & 31;
    int s = offs[node], eend = offs[node + 1];
    float a0 = 0.f, a1 = 0.f, a2 = 0.f, a3 = 0.f;
    for (int i = s; i < eend; ++i) {
        int2 p = epack[i];
        float f = __int_as_float(p.y);
        ushort4 xv = *(const ushort4*)&xh[(size_t)p.x * HIDDEN + lane * 4];
        a0 = fmaf(bf2f(xv.x), f, a0);
        a1 = fmaf(bf2f(xv.y), f, a1);
        a2 = fmaf(bf2f(xv.z), f, a2);
        a3 = fmaf(bf2f(xv.w), f, a3);
    }
    ushort4 o;
    o.x = (unsigned short)f2bf(a0);
    o.y = (unsigned short)f2bf(a1);
    o.z = (unsigned short)f2bf(a2);
    o.w = (unsigned short)f2bf(a3);
    *(ushort4*)&aggh[(size_t)node * HIDDEN + lane * 4] = o;
}

// fp32 variant (tier B/C): writes agg fp32 into io
__global__ __launch_bounds__(256) void gather_kernel(const int* __restrict__ offs,
                                                     const int2* __restrict__ epack,
                                                     const float* __restrict__ x,
                                                     float* __restrict__ agg, int N) {
    int t = threadIdx.x;
    int node = blockIdx.x * 8 + (t >> 5);
    if (node >= N) return;
    int lane = t & 31;
    int s = offs[node], eend = offs[node + 1];
    float4 acc = make_float4(0.f, 0.f, 0.f, 0.f);
    for (int i = s; i < eend; ++i) {
        int2 p = epack[i];
        float f = __int_as_float(p.y);
        const float4 xv = *(const float4*)&x[(size_t)p.x * HIDDEN + lane * 4];
        acc.x = fmaf(xv.x, f, acc.x);
        acc.y = fmaf(xv.y, f, acc.y);
        acc.z = fmaf(xv.z, f, acc.z);
        acc.w = fmaf(xv.w, f, acc.w);
    }
    *(float4*)&agg[(size_t)node * HIDDEN + lane * 4] = acc;
}

// ---------------------------------------------------------------------------
// MFMA MLP. bf-variant reads A directly from aggh (bf16); writes io fp32.
//   out = scf * (softplus(A @ Wi1 + bi1) @ Wi2) + shf
// ---------------------------------------------------------------------------
#define HROW 136   // 128 + 8 shorts pad -> 68-dword row stride (2-way max aliasing)

__global__ __launch_bounds__(256) void mlp_mfma_bf_kernel(
    const short* __restrict__ aggh, float* __restrict__ io,
    const short* __restrict__ W1T, const short* __restrict__ W2T,
    const float* __restrict__ bi1,
    const float* __restrict__ scf, const float* __restrict__ shf,
    int N) {
    __shared__ short hS[64 * HROW];   // 17 KB

    const int t = threadIdx.x;
    const int wave = t >> 6;
    const int lane = t & 63;
    const int quad = lane >> 4;
    const int m16  = lane & 15;
    const int row0 = blockIdx.x * 64 + wave * 16;
    const int arow = row0 + m16;

    f32x4 acc[8];
    #pragma unroll
    for (int ct = 0; ct < 8; ++ct) acc[ct] = (f32x4)(0.f);

    // ---- phase A: acc = aggh @ W1 (A-frag straight from bf16 memory)
    #pragma unroll
    for (int ks = 0; ks < 4; ++ks) {
        bf16x8 a;
        if (arow < N) {
            a = *(const bf16x8*)&aggh[(size_t)arow * HIDDEN + ks * 32 + quad * 8];
        } else {
            #pragma unroll
            for (int j = 0; j < 8; ++j) a[j] = 0;
        }
        #pragma unroll
        for (int ct = 0; ct < 8; ++ct) {
            bf16x8 b = *(const bf16x8*)&W1T[(ct * 16 + m16) * HIDDEN + ks * 32 + quad * 8];
            acc[ct] = __builtin_amdgcn_mfma_f32_16x16x32_bf16(a, b, acc[ct], 0, 0, 0);
        }
    }

    // epilogue A: +bi1, softplus, bf16 -> LDS
    #pragma unroll
    for (int ct = 0; ct < 8; ++ct) {
        int col = ct * 16 + m16;
        float b1 = bi1[col];
        #pragma unroll
        for (int r = 0; r < 4; ++r) {
            int lrow = wave * 16 + quad * 4 + r;
            float v = acc[ct][r] + b1;
            float h = (v > 20.f) ? v : log1pf(__expf(v));
            hS[lrow * HROW + col] = f2bf(h);
            acc[ct][r] = 0.f;
        }
    }
    __syncthreads();

    // ---- phase B: acc = h @ W2
    #pragma unroll
    for (int ks = 0; ks < 4; ++ks) {
        bf16x8 a = *(const bf16x8*)&hS[(wave * 16 + m16) * HROW + ks * 32 + quad * 8];
        #pragma unroll
        for (int ct = 0; ct < 8; ++ct) {
            bf16x8 b = *(const bf16x8*)&W2T[(ct * 16 + m16) * HIDDEN + ks * 32 + quad * 8];
            acc[ct] = __builtin_amdgcn_mfma_f32_16x16x32_bf16(a, b, acc[ct], 0, 0, 0);
        }
    }

    // epilogue B: BN (folded) + store fp32
    #pragma unroll
    for (int ct = 0; ct < 8; ++ct) {
        int col = ct * 16 + m16;
        float sc = scf[col], sh = shf[col];
        #pragma unroll
        for (int r = 0; r < 4; ++r) {
            int grow = row0 + quad * 4 + r;
            if (grow < N)
                io[(size_t)grow * HIDDEN + col] = fmaf(acc[ct][r], sc, sh);
        }
    }
}

// fp32-A variant (tier B/C): in-place on io
__global__ __launch_bounds__(256) void mlp_mfma_kernel(
    float* io,
    const short* __restrict__ W1T, const short* __restrict__ W2T,
    const float* __restrict__ bi1,
    const float* __restrict__ scf, const float* __restrict__ shf,
    int N) {
    __shared__ short hS[64 * HROW];

    const int t = threadIdx.x;
    const int wave = t >> 6;
    const int lane = t & 63;
    const int quad = lane >> 4;
    const int m16  = lane & 15;
    const int row0 = blockIdx.x * 64 + wave * 16;
    const int arow = row0 + m16;

    f32x4 acc[8];
    #pragma unroll
    for (int ct = 0; ct < 8; ++ct) acc[ct] = (f32x4)(0.f);

    #pragma unroll
    for (int ks = 0; ks < 4; ++ks) {
        bf16x8 a;
        if (arow < N) {
            const float* ap = &io[(size_t)arow * HIDDEN + ks * 32 + quad * 8];
            float4 v0 = *(const float4*)ap;
            float4 v1 = *(const float4*)(ap + 4);
            a[0] = f2bf(v0.x); a[1] = f2bf(v0.y); a[2] = f2bf(v0.z); a[3] = f2bf(v0.w);
            a[4] = f2bf(v1.x); a[5] = f2bf(v1.y); a[6] = f2bf(v1.z); a[7] = f2bf(v1.w);
        } else {
            #pragma unroll
            for (int j = 0; j < 8; ++j) a[j] = 0;
        }
        #pragma unroll
        for (int ct = 0; ct < 8; ++ct) {
            bf16x8 b = *(const bf16x8*)&W1T[(ct * 16 + m16) * HIDDEN + ks * 32 + quad * 8];
            acc[ct] = __builtin_amdgcn_mfma_f32_16x16x32_bf16(a, b, acc[ct], 0, 0, 0);
        }
    }

    #pragma unroll
    for (int ct = 0; ct < 8; ++ct) {
        int col = ct * 16 + m16;
        float b1 = bi1[col];
        #pragma unroll
        for (int r = 0; r < 4; ++r) {
            int lrow = wave * 16 + quad * 4 + r;
            float v = acc[ct][r] + b1;
            float h = (v > 20.f) ? v : log1pf(__expf(v));
            hS[lrow * HROW + col] = f2bf(h);
            acc[ct][r] = 0.f;
        }
    }
    __syncthreads();

    #pragma unroll
    for (int ks = 0; ks < 4; ++ks) {
        bf16x8 a = *(const bf16x8*)&hS[(wave * 16 + m16) * HROW + ks * 32 + quad * 8];
        #pragma unroll
        for (int ct = 0; ct < 8; ++ct) {
            bf16x8 b = *(const bf16x8*)&W2T[(ct * 16 + m16) * HIDDEN + ks * 32 + quad * 8];
            acc[ct] = __builtin_amdgcn_mfma_f32_16x16x32_bf16(a, b, acc[ct], 0, 0, 0);
        }
    }

    #pragma unroll
    for (int ct = 0; ct < 8; ++ct) {
        int col = ct * 16 + m16;
        float sc = scf[col], sh = shf[col];
        #pragma unroll
        for (int r = 0; r < 4; ++r) {
            int grow = row0 + quad * 4 + r;
            if (grow < N)
                io[(size_t)grow * HIDDEN + col] = fmaf(acc[ct][r], sc, sh);
        }
    }
}

// ---------------------------------------------------------------------------
// Fallback path kernels (tiny ws): atomic scatter + fp32 vector MLP
// ---------------------------------------------------------------------------
__global__ void edge_filter_kernel(const float* __restrict__ ew,
                                   const float* __restrict__ Wf1, const float* __restrict__ bf1,
                                   const float* __restrict__ wsum, const float* __restrict__ bsum,
                                   float* __restrict__ fs, int E) {
    __shared__ float sW[NFILT], sB[NFILT], sS[NFILT];
    if (threadIdx.x < NFILT) {
        sW[threadIdx.x] = Wf1[threadIdx.x];
        sB[threadIdx.x] = bf1[threadIdx.x];
        sS[threadIdx.x] = wsum[threadIdx.x];
    }
    __syncthreads();
    int e = blockIdx.x * blockDim.x + threadIdx.x;
    if (e >= E) return;
    fs[e] = edge_coeff(ew[e], sW, sB, sS, *bsum);
}

__global__ void scatter_kernel(const int* __restrict__ rows, const int* __restrict__ cols,
                               const float* __restrict__ x, const float* __restrict__ fs,
                               float* __restrict__ agg, int E) {
    int t = threadIdx.x;
    int e = blockIdx.x * 8 + (t >> 5);
    if (e >= E) return;
    int lane = t & 31;
    int r = rows[e];
    int c = cols[e];
    float f = fs[e];
    const float4 xv = *(const float4*)&x[c * HIDDEN + lane * 4];
    float* dst = &agg[r * HIDDEN + lane * 4];
    atomicAdd(dst + 0, xv.x * f);
    atomicAdd(dst + 1, xv.y * f);
    atomicAdd(dst + 2, xv.z * f);
    atomicAdd(dst + 3, xv.w * f);
}

__global__ __launch_bounds__(256) void mlp_kernel(
    float* __restrict__ io,
    const float* __restrict__ Wi1, const float* __restrict__ bi1,
    const float* __restrict__ Wi2, const float* __restrict__ bi2,
    const float* __restrict__ gamma, const float* __restrict__ beta,
    const float* __restrict__ mean, const float* __restrict__ var,
    int N) {
    __shared__ float As[64 * HIDDEN];
    __shared__ float Wh[64 * HIDDEN];

    const int t = threadIdx.x;
    const int row0 = blockIdx.x * 64;
    const int col4 = (t & 31) * 4;
    const int rgrp = t >> 5;

    #pragma unroll
    for (int i = 0; i < 8; ++i) {
        int f4 = t + 256 * i;
        int r = f4 >> 5, c4 = (f4 & 31) * 4;
        int node = row0 + r;
        float4 v = make_float4(0.f, 0.f, 0.f, 0.f);
        if (node < N) v = *(const float4*)&io[node * HIDDEN + c4];
        *(float4*)&As[r * HIDDEN + c4] = v;
    }

    float acc[8][4];
    #pragma unroll
    for (int r = 0; r < 8; ++r)
        for (int j = 0; j < 4; ++j) acc[r][j] = 0.f;

    for (int kh = 0; kh < 2; ++kh) {
        __syncthreads();
        #pragma unroll
        for (int i = 0; i < 8; ++i) {
            int f4 = t + 256 * i;
            int kr = f4 >> 5, c4 = (f4 & 31) * 4;
            *(float4*)&Wh[kr * HIDDEN + c4] = *(const float4*)&Wi1[(kh * 64 + kr) * HIDDEN + c4];
        }
        __syncthreads();
        for (int k = 0; k < 64; ++k) {
            float4 w = *(const float4*)&Wh[k * HIDDEN + col4];
            #pragma unroll
            for (int r = 0; r < 8; ++r) {
                float a = As[(rgrp + 8 * r) * HIDDEN + kh * 64 + k];
                acc[r][0] = fmaf(a, w.x, acc[r][0]);
                acc[r][1] = fmaf(a, w.y, acc[r][1]);
                acc[r][2] = fmaf(a, w.z, acc[r][2]);
                acc[r][3] = fmaf(a, w.w, acc[r][3]);
            }
        }
    }
    __syncthreads();

    {
        float4 b = *(const float4*)&bi1[col4];
        float bv[4] = {b.x, b.y, b.z, b.w};
        #pragma unroll
        for (int r = 0; r < 8; ++r) {
            float hv[4];
            #pragma unroll
            for (int j = 0; j < 4; ++j) {
                float v = acc[r][j] + bv[j];
                hv[j] = (v > 20.f) ? v : log1pf(__expf(v));
                acc[r][j] = 0.f;
            }
            *(float4*)&As[(rgrp + 8 * r) * HIDDEN + col4] =
                make_float4(hv[0], hv[1], hv[2], hv[3]);
        }
    }

    for (int kh = 0; kh < 2; ++kh) {
        __syncthreads();
        #pragma unroll
        for (int i = 0; i < 8; ++i) {
            int f4 = t + 256 * i;
            int kr = f4 >> 5, c4 = (f4 & 31) * 4;
            *(float4*)&Wh[kr * HIDDEN + c4] = *(const float4*)&Wi2[(kh * 64 + kr) * HIDDEN + c4];
        }
        __syncthreads();
        for (int k = 0; k < 64; ++k) {
            float4 w = *(const float4*)&Wh[k * HIDDEN + col4];
            #pragma unroll
            for (int r = 0; r < 8; ++r) {
                float a = As[(rgrp + 8 * r) * HIDDEN + kh * 64 + k];
                acc[r][0] = fmaf(a, w.x, acc[r][0]);
                acc[r][1] = fmaf(a, w.y, acc[r][1]);
                acc[r][2] = fmaf(a, w.z, acc[r][2]);
                acc[r][3] = fmaf(a, w.w, acc[r][3]);
            }
        }
    }

    {
        float4 b2 = *(const float4*)&bi2[col4];
        float4 g  = *(const float4*)&gamma[col4];
        float4 be = *(const float4*)&beta[col4];
        float4 mu = *(const float4*)&mean[col4];
        float4 va = *(const float4*)&var[col4];
        float bv[4]  = {b2.x, b2.y, b2.z, b2.w};
        float gv[4]  = {g.x, g.y, g.z, g.w};
        float bev[4] = {be.x, be.y, be.z, be.w};
        float muv[4] = {mu.x, mu.y, mu.z, mu.w};
        float vav[4] = {va.x, va.y, va.z, va.w};
        float sc[4];
        #pragma unroll
        for (int j = 0; j < 4; ++j) sc[j] = gv[j] * rsqrtf(vav[j] + 1e-3f);
        #pragma unroll
        for (int r = 0; r < 8; ++r) {
            int node = row0 + rgrp + 8 * r;
            if (node < N) {
                float o[4];
                #pragma unroll
                for (int j = 0; j < 4; ++j)
                    o[j] = (acc[r][j] + bv[j] - muv[j]) * sc[j] + bev[j];
                *(float4*)&io[node * HIDDEN + col4] = make_float4(o[0], o[1], o[2], o[3]);
            }
        }
    }
}

extern "C" void kernel_launch(void* const* d_in, const int* in_sizes, int n_in,
                              void* d_out, int out_size, void* d_ws, size_t ws_size,
                              hipStream_t stream) {
    const float* x    = (const float*)d_in[0];
    const int*   ei   = (const int*)d_in[1];
    const float* ew   = (const float*)d_in[2];
    // d_in[3] = edge_attr: unused by the reference math
    const float* Wf1  = (const float*)d_in[4];
    const float* bf1  = (const float*)d_in[5];
    const float* Wf2  = (const float*)d_in[6];
    const float* bf2  = (const float*)d_in[7];
    const float* Wi1  = (const float*)d_in[8];
    const float* bi1  = (const float*)d_in[9];
    const float* Wi2  = (const float*)d_in[10];
    const float* bi2  = (const float*)d_in[11];
    const float* gam  = (const float*)d_in[12];
    const float* bet  = (const float*)d_in[13];
    const float* mmu  = (const float*)d_in[14];
    const float* mva  = (const float*)d_in[15];

    const int N = in_sizes[0] / HIDDEN;
    const int E = in_sizes[2];
    const int* rows = ei;
    const int* cols = ei + E;

    float* io = (float*)d_out;     // final output; tier B/C also use it as agg

    const int B = (N + SCAN_B - 1) / SCAN_B;

    // ws layout:
    //   deg[N] | offs[N+1] | bsums[B] | wsum[64] | bsum[1] | lut[LUTK+1] | pad |
    //   epack[E] int2 | pad | W1T | W2T | scf[128] | shf[128] | pad |
    //   rank[E] | pad | xh[N*128] bf16 | aggh[N*128] bf16
    char* ws = (char*)d_ws;
    int*   deg    = (int*)ws;
    int*   offs   = deg + N;
    int*   bsums  = offs + N + 1;
    float* wsumv  = (float*)(bsums + B);
    float* bsumv  = wsumv + NFILT;
    float* lut    = bsumv + 1;
    size_t hdr_ints  = (size_t)(2 * N + 1 + B + NFILT + 1 + LUTK + 1);
    size_t epack_off = ((hdr_ints * 4) + 15) & ~(size_t)15;
    int2*  epack  = (int2*)(ws + epack_off);
    size_t wT_off = (epack_off + (size_t)E * sizeof(int2) + 15) & ~(size_t)15;
    short* W1T    = (short*)(ws + wT_off);
    short* W2T    = W1T + HIDDEN * HIDDEN;
    float* scf    = (float*)(W2T + HIDDEN * HIDDEN);
    float* shf    = scf + HIDDEN;
    size_t base_need = wT_off + 2 * HIDDEN * HIDDEN * sizeof(short) + 2 * HIDDEN * sizeof(float);
    size_t rank_off  = (base_need + 15) & ~(size_t)15;
    int*   rank   = (int*)(ws + rank_off);
    size_t rank_need = rank_off + (size_t)E * sizeof(int);
    size_t xh_off    = (rank_need + 15) & ~(size_t)15;
    short* xh     = (short*)(ws + xh_off);
    short* aggh   = xh + (size_t)N * HIDDEN;
    size_t bf_need = xh_off + 2 * (size_t)N * HIDDEN * sizeof(short);

    if (ws_size >= base_need && B <= SCAN_B) {
        const bool use_rank = (ws_size >= rank_need);
        const bool use_bf   = (ws_size >= bf_need);   // implies use_rank
        hipMemsetAsync(deg, 0, (size_t)N * sizeof(int), stream);
        wsum_kernel<<<1, 64, 0, stream>>>(Wf2, bf2, wsumv, bsumv);
        lut_kernel<<<(LUTK + 256) / 256, 256, 0, stream>>>(Wf1, bf1, wsumv, bsumv, lut);
        prep_w_kernel<<<128, 256, 0, stream>>>(Wi1, Wi2, W1T, W2T);
        prep_bn_kernel<<<1, HIDDEN, 0, stream>>>(bi2, gam, bet, mmu, mva, scf, shf);
        if (use_bf) {
            int total8 = N * (HIDDEN / 8);
            x2bf_kernel<<<(total8 + 255) / 256, 256, 0, stream>>>(x, xh, total8);
        }
        if (use_rank)
            count_rank_kernel<<<(E + 255) / 256, 256, 0, stream>>>(rows, deg, rank, E);
        else
            count_kernel<<<(E + 255) / 256, 256, 0, stream>>>(rows, deg, E);
        scan_p1<<<B, SCAN_B, 0, stream>>>(deg, bsums, N);
        scan_p2<<<1, SCAN_B, 0, stream>>>(bsums, B);
        if (use_rank) {
            scan_p3_t<false><<<B, SCAN_B, 0, stream>>>(deg, bsums, offs, N);
            fill_rank_kernel<<<(E + 255) / 256, 256, 0, stream>>>(rows, cols, ew, rank,
                                                                  offs, lut, epack, E);
        } else {
            scan_p3_t<true><<<B, SCAN_B, 0, stream>>>(deg, bsums, offs, N);
            fill_cursor_kernel<<<(E + 255) / 256, 256, 0, stream>>>(rows, cols, ew, deg,
                                                                    lut, epack, E);
        }
        if (use_bf) {
            gather_bf_kernel<<<(N + 7) / 8, 256, 0, stream>>>(offs, epack, xh, aggh, N);
            mlp_mfma_bf_kernel<<<(N + 63) / 64, 256, 0, stream>>>(aggh, io, W1T, W2T,
                                                                  bi1, scf, shf, N);
        } else {
            gather_kernel<<<(N + 7) / 8, 256, 0, stream>>>(offs, epack, x, io, N);
            mlp_mfma_kernel<<<(N + 63) / 64, 256, 0, stream>>>(io, W1T, W2T, bi1, scf, shf, N);
        }
    } else {
        // ---- fallback: atomic scatter + fp32 MLP ----
        float* fs = (float*)d_ws;             // [E]
        float* w2 = fs + E;                   // [64]
        float* b2 = w2 + NFILT;               // [1]
        hipMemsetAsync(d_out, 0, (size_t)out_size * sizeof(float), stream);
        wsum_kernel<<<1, 64, 0, stream>>>(Wf2, bf2, w2, b2);
        edge_filter_kernel<<<(E + 255) / 256, 256, 0, stream>>>(ew, Wf1, bf1, w2, b2, fs, E);
        scatter_kernel<<<(E + 7) / 8, 256, 0, stream>>>(rows, cols, x, fs, io, E);
        mlp_kernel<<<(N + 63) / 64, 256, 0, stream>>>(io, Wi1, bi1, Wi2, bi2,
                                                      gam, bet, mmu, mva, N);
    }
}

// Round 7
// 428.979 us; speedup vs baseline: 6.9655x; 1.0566x over previous
//
#include <hip/hip_runtime.h>
#include <math.h>

#define HIDDEN 128
#define NFILT 64
#define SCAN_B 1024
#define LUTK 2048   // LUT entries over w in [0,8]; lerp err ~5e-7

typedef __attribute__((ext_vector_type(8))) short bf16x8;
typedef __attribute__((ext_vector_type(4))) float f32x4;

__device__ __forceinline__ short f2bf(float f) {
    unsigned u = __float_as_uint(f);
    unsigned r = (u + 0x7fffu + ((u >> 16) & 1u)) >> 16;   // RNE
    return (short)r;
}
__device__ __forceinline__ float bf2f(unsigned short u) {
    return __uint_as_float(((unsigned)u) << 16);
}

// ---------------------------------------------------------------------------
// wsum[j] = sum_f Wf2[j][f]; bsum = sum_f bf2[f]
// ---------------------------------------------------------------------------
__global__ void wsum_kernel(const float* __restrict__ Wf2, const float* __restrict__ bf2,
                            float* __restrict__ wsum, float* __restrict__ bsum) {
    int j = threadIdx.x;  // 0..63
    float s = 0.f;
    for (int f = 0; f < NFILT; ++f) s += Wf2[j * NFILT + f];
    wsum[j] = s;
    if (j == 0) {
        float b = 0.f;
        for (int f = 0; f < NFILT; ++f) b += bf2[f];
        *bsum = b;
    }
}

__device__ __forceinline__ float edge_coeff(float w,
                                            const float* sW, const float* sB,
                                            const float* sS, float bsum) {
    float s = fmaf(w, 0.25f, -1.0f);          // w * (2/8) - 1
    float acc = bsum;
    #pragma unroll 8
    for (int j = 0; j < NFILT; ++j)
        acc += tanhf(fmaf(s, sW[j], sB[j])) * sS[j];
    float cut = (w <= 8.0f) ? 0.5f * (cosf(w * 0.39269908169872414f) + 1.0f) : 0.0f;
    return acc * cut;
}

// LUT over the scalar filter function g(w), w in [0,8], LUTK+1 samples
__global__ void lut_kernel(const float* __restrict__ Wf1, const float* __restrict__ bf1,
                           const float* __restrict__ wsum, const float* __restrict__ bsum,
                           float* __restrict__ lut) {
    int i = blockIdx.x * 256 + threadIdx.x;
    if (i > LUTK) return;
    float w = 8.0f * (float)i / (float)LUTK;
    lut[i] = edge_coeff(w, Wf1, bf1, wsum, *bsum);
}

__device__ __forceinline__ float lut_eval(const float* sl, float w) {
    float t = w * ((float)LUTK / 8.0f);
    t = fminf(fmaxf(t, 0.f), (float)LUTK);
    int i = (int)t;
    i = min(i, LUTK - 1);
    return fmaf(t - (float)i, sl[i + 1] - sl[i], sl[i]);
}

// ---------------------------------------------------------------------------
// Prep: W1T/W2T = bf16 transpose of Wi1/Wi2; BN folded; x -> bf16
// ---------------------------------------------------------------------------
__global__ void prep_w_kernel(const float* __restrict__ Wi1, const float* __restrict__ Wi2,
                              short* __restrict__ W1T, short* __restrict__ W2T) {
    int idx = blockIdx.x * 256 + threadIdx.x;   // 0..32767
    const float* src = (idx < 16384) ? Wi1 : Wi2;
    short* dst = (idx < 16384) ? W1T : W2T;
    int i = idx & 16383;
    int k = i >> 7, n = i & 127;
    dst[n * HIDDEN + k] = f2bf(src[i]);
}

__global__ void prep_bn_kernel(const float* __restrict__ bi2,
                               const float* __restrict__ gamma, const float* __restrict__ beta,
                               const float* __restrict__ mean, const float* __restrict__ var,
                               float* __restrict__ scf, float* __restrict__ shf) {
    int j = threadIdx.x;  // 0..127
    float sc = gamma[j] * rsqrtf(var[j] + 1e-3f);
    scf[j] = sc;
    shf[j] = (bi2[j] - mean[j]) * sc + beta[j];
}

// x (fp32) -> xh (bf16), 8 elems/thread
__global__ void x2bf_kernel(const float* __restrict__ x, short* __restrict__ xh, int total8) {
    int i = blockIdx.x * 256 + threadIdx.x;
    if (i >= total8) return;
    const float4 v0 = *(const float4*)&x[(size_t)i * 8];
    const float4 v1 = *(const float4*)&x[(size_t)i * 8 + 4];
    bf16x8 o;
    o[0] = f2bf(v0.x); o[1] = f2bf(v0.y); o[2] = f2bf(v0.z); o[3] = f2bf(v0.w);
    o[4] = f2bf(v1.x); o[5] = f2bf(v1.y); o[6] = f2bf(v1.z); o[7] = f2bf(v1.w);
    *(bf16x8*)&xh[(size_t)i * 8] = o;
}

// ---------------------------------------------------------------------------
// CSR build
// ---------------------------------------------------------------------------
__global__ void count_rank_kernel(const int* __restrict__ rows, int* __restrict__ deg,
                                  int* __restrict__ rank, int E) {
    int e = blockIdx.x * blockDim.x + threadIdx.x;
    if (e < E) rank[e] = atomicAdd(&deg[rows[e]], 1);
}

__global__ void count_kernel(const int* __restrict__ rows, int* __restrict__ deg, int E) {
    int e = blockIdx.x * blockDim.x + threadIdx.x;
    if (e < E) atomicAdd(&deg[rows[e]], 1);
}

__global__ __launch_bounds__(SCAN_B) void scan_p1(const int* __restrict__ deg,
                                                  int* __restrict__ bsums, int N) {
    __shared__ int red[SCAN_B];
    int i = blockIdx.x * SCAN_B + threadIdx.x;
    red[threadIdx.x] = (i < N) ? deg[i] : 0;
    __syncthreads();
    for (int off = SCAN_B / 2; off > 0; off >>= 1) {
        if (threadIdx.x < off) red[threadIdx.x] += red[threadIdx.x + off];
        __syncthreads();
    }
    if (threadIdx.x == 0) bsums[blockIdx.x] = red[0];
}

__global__ __launch_bounds__(SCAN_B) void scan_p2(int* __restrict__ bsums, int B) {
    __shared__ int part[SCAN_B];
    int t = threadIdx.x;
    part[t] = (t < B) ? bsums[t] : 0;
    __syncthreads();
    for (int off = 1; off < SCAN_B; off <<= 1) {
        int v = (t >= off) ? part[t - off] : 0;
        __syncthreads();
        part[t] += v;
        __syncthreads();
    }
    if (t < B) bsums[t] = (t == 0) ? 0 : part[t - 1];   // exclusive
}

template <bool WRITE_CURSOR>
__global__ __launch_bounds__(SCAN_B) void scan_p3_t(int* __restrict__ deg,
                                                    const int* __restrict__ bsums,
                                                    int* __restrict__ offs, int N) {
    __shared__ int part[SCAN_B];
    int t = threadIdx.x;
    int i = blockIdx.x * SCAN_B + t;
    int d = (i < N) ? deg[i] : 0;
    part[t] = d;
    __syncthreads();
    for (int off = 1; off < SCAN_B; off <<= 1) {
        int v = (t >= off) ? part[t - off] : 0;
        __syncthreads();
        part[t] += v;
        __syncthreads();
    }
    int pre = bsums[blockIdx.x] + part[t] - d;
    if (i < N) {
        offs[i] = pre;
        if (WRITE_CURSOR) deg[i] = pre;   // deg becomes cursor
        if (i == N - 1) offs[N] = pre + d;
    }
}

// fill (rank path): no atomics — pos = offs[row] + rank
__global__ __launch_bounds__(256) void fill_rank_kernel(
    const int* __restrict__ rows, const int* __restrict__ cols,
    const float* __restrict__ ew, const int* __restrict__ rank,
    const int* __restrict__ offs, const float* __restrict__ lut,
    int2* __restrict__ epack, int E) {
    __shared__ float sl[LUTK + 1];
    for (int i = threadIdx.x; i <= LUTK; i += 256) sl[i] = lut[i];
    __syncthreads();
    int e = blockIdx.x * 256 + threadIdx.x;
    if (e >= E) return;
    float f = lut_eval(sl, ew[e]);
    int pos = offs[rows[e]] + rank[e];
    epack[pos] = make_int2(cols[e], __float_as_int(f));
}

// fill (cursor path)
__global__ __launch_bounds__(256) void fill_cursor_kernel(
    const int* __restrict__ rows, const int* __restrict__ cols,
    const float* __restrict__ ew, int* __restrict__ cursor,
    const float* __restrict__ lut, int2* __restrict__ epack, int E) {
    __shared__ float sl[LUTK + 1];
    for (int i = threadIdx.x; i <= LUTK; i += 256) sl[i] = lut[i];
    __syncthreads();
    int e = blockIdx.x * 256 + threadIdx.x;
    if (e >= E) return;
    float f = lut_eval(sl, ew[e]);
    int pos = atomicAdd(&cursor[rows[e]], 1);
    epack[pos] = make_int2(cols[e], __float_as_int(f));
}

// ---------------------------------------------------------------------------
// gather (bf16 x): 32 lanes/node, ushort4/lane = 256 B per edge row.
// 4-wide software pipeline: 4 epack loads -> 4 independent xh loads -> 16 FMA.
// Two serial memory latencies per 4 edges instead of per edge (MLP x4).
// ---------------------------------------------------------------------------
__global__ __launch_bounds__(256) void gather_bf_kernel(const int* __restrict__ offs,
                                                        const int2* __restrict__ epack,
                                                        const short* __restrict__ xh,
                                                        short* __restrict__ aggh, int N) {
    int t = threadIdx.x;
    int node = blockIdx.x * 8 + (t >> 5);
    if (node >= N) return;
    int lane = t & 31;
    int s = offs[node], eend = offs[node + 1];
    float a0 = 0.f, a1 = 0.f, a2 = 0.f, a3 = 0.f;

    int i = s;
    for (; i + 4 <= eend; i += 4) {
        int2 p0 = epack[i];
        int2 p1 = epack[i + 1];
        int2 p2 = epack[i + 2];
        int2 p3 = epack[i + 3];
        ushort4 x0 = *(const ushort4*)&xh[(size_t)p0.x * HIDDEN + lane * 4];
        ushort4 x1 = *(const ushort4*)&xh[(size_t)p1.x * HIDDEN + lane * 4];
        ushort4 x2 = *(const ushort4*)&xh[(size_t)p2.x * HIDDEN + lane * 4];
        ushort4 x3 = *(const ushort4*)&xh[(size_t)p3.x * HIDDEN + lane * 4];
        float f0 = __int_as_float(p0.y), f1 = __int_as_float(p1.y);
        float f2 = __int_as_float(p2.y), f3 = __int_as_float(p3.y);
        a0 = fmaf(bf2f(x0.x), f0, a0); a1 = fmaf(bf2f(x0.y), f0, a1);
        a2 = fmaf(bf2f(x0.z), f0, a2); a3 = fmaf(bf2f(x0.w), f0, a3);
        a0 = fmaf(bf2f(x1.x), f1, a0); a1 = fmaf(bf2f(x1.y), f1, a1);
        a2 = fmaf(bf2f(x1.z), f1, a2); a3 = fmaf(bf2f(x1.w), f1, a3);
        a0 = fmaf(bf2f(x2.x), f2, a0); a1 = fmaf(bf2f(x2.y), f2, a1);
        a2 = fmaf(bf2f(x2.z), f2, a2); a3 = fmaf(bf2f(x2.w), f2, a3);
        a0 = fmaf(bf2f(x3.x), f3, a0); a1 = fmaf(bf2f(x3.y), f3, a1);
        a2 = fmaf(bf2f(x3.z), f3, a2); a3 = fmaf(bf2f(x3.w), f3, a3);
    }
    for (; i < eend; ++i) {
        int2 p = epack[i];
        float f = __int_as_float(p.y);
        ushort4 xv = *(const ushort4*)&xh[(size_t)p.x * HIDDEN + lane * 4];
        a0 = fmaf(bf2f(xv.x), f, a0);
        a1 = fmaf(bf2f(xv.y), f, a1);
        a2 = fmaf(bf2f(xv.z), f, a2);
        a3 = fmaf(bf2f(xv.w), f, a3);
    }
    ushort4 o;
    o.x = (unsigned short)f2bf(a0);
    o.y = (unsigned short)f2bf(a1);
    o.z = (unsigned short)f2bf(a2);
    o.w = (unsigned short)f2bf(a3);
    *(ushort4*)&aggh[(size_t)node * HIDDEN + lane * 4] = o;
}

// fp32 variant (tier B/C): writes agg fp32 into io; same 4-wide pipeline
__global__ __launch_bounds__(256) void gather_kernel(const int* __restrict__ offs,
                                                     const int2* __restrict__ epack,
                                                     const float* __restrict__ x,
                                                     float* __restrict__ agg, int N) {
    int t = threadIdx.x;
    int node = blockIdx.x * 8 + (t >> 5);
    if (node >= N) return;
    int lane = t & 31;
    int s = offs[node], eend = offs[node + 1];
    float4 acc = make_float4(0.f, 0.f, 0.f, 0.f);
    int i = s;
    for (; i + 2 <= eend; i += 2) {
        int2 p0 = epack[i];
        int2 p1 = epack[i + 1];
        float4 x0 = *(const float4*)&x[(size_t)p0.x * HIDDEN + lane * 4];
        float4 x1 = *(const float4*)&x[(size_t)p1.x * HIDDEN + lane * 4];
        float f0 = __int_as_float(p0.y), f1 = __int_as_float(p1.y);
        acc.x = fmaf(x0.x, f0, acc.x); acc.y = fmaf(x0.y, f0, acc.y);
        acc.z = fmaf(x0.z, f0, acc.z); acc.w = fmaf(x0.w, f0, acc.w);
        acc.x = fmaf(x1.x, f1, acc.x); acc.y = fmaf(x1.y, f1, acc.y);
        acc.z = fmaf(x1.z, f1, acc.z); acc.w = fmaf(x1.w, f1, acc.w);
    }
    for (; i < eend; ++i) {
        int2 p = epack[i];
        float f = __int_as_float(p.y);
        const float4 xv = *(const float4*)&x[(size_t)p.x * HIDDEN + lane * 4];
        acc.x = fmaf(xv.x, f, acc.x);
        acc.y = fmaf(xv.y, f, acc.y);
        acc.z = fmaf(xv.z, f, acc.z);
        acc.w = fmaf(xv.w, f, acc.w);
    }
    *(float4*)&agg[(size_t)node * HIDDEN + lane * 4] = acc;
}

// ---------------------------------------------------------------------------
// MFMA MLP. bf-variant reads A directly from aggh (bf16); writes io fp32.
//   out = scf * (softplus(A @ Wi1 + bi1) @ Wi2) + shf
// ---------------------------------------------------------------------------
#define HROW 136   // 128 + 8 shorts pad -> 68-dword row stride (2-way max aliasing)

__global__ __launch_bounds__(256) void mlp_mfma_bf_kernel(
    const short* __restrict__ aggh, float* __restrict__ io,
    const short* __restrict__ W1T, const short* __restrict__ W2T,
    const float* __restrict__ bi1,
    const float* __restrict__ scf, const float* __restrict__ shf,
    int N) {
    __shared__ short hS[64 * HROW];   // 17 KB

    const int t = threadIdx.x;
    const int wave = t >> 6;
    const int lane = t & 63;
    const int quad = lane >> 4;
    const int m16  = lane & 15;
    const int row0 = blockIdx.x * 64 + wave * 16;
    const int arow = row0 + m16;

    f32x4 acc[8];
    #pragma unroll
    for (int ct = 0; ct < 8; ++ct) acc[ct] = (f32x4)(0.f);

    // ---- phase A: acc = aggh @ W1 (A-frag straight from bf16 memory)
    #pragma unroll
    for (int ks = 0; ks < 4; ++ks) {
        bf16x8 a;
        if (arow < N) {
            a = *(const bf16x8*)&aggh[(size_t)arow * HIDDEN + ks * 32 + quad * 8];
        } else {
            #pragma unroll
            for (int j = 0; j < 8; ++j) a[j] = 0;
        }
        #pragma unroll
        for (int ct = 0; ct < 8; ++ct) {
            bf16x8 b = *(const bf16x8*)&W1T[(ct * 16 + m16) * HIDDEN + ks * 32 + quad * 8];
            acc[ct] = __builtin_amdgcn_mfma_f32_16x16x32_bf16(a, b, acc[ct], 0, 0, 0);
        }
    }

    // epilogue A: +bi1, softplus, bf16 -> LDS
    #pragma unroll
    for (int ct = 0; ct < 8; ++ct) {
        int col = ct * 16 + m16;
        float b1 = bi1[col];
        #pragma unroll
        for (int r = 0; r < 4; ++r) {
            int lrow = wave * 16 + quad * 4 + r;
            float v = acc[ct][r] + b1;
            float h = (v > 20.f) ? v : log1pf(__expf(v));
            hS[lrow * HROW + col] = f2bf(h);
            acc[ct][r] = 0.f;
        }
    }
    __syncthreads();

    // ---- phase B: acc = h @ W2
    #pragma unroll
    for (int ks = 0; ks < 4; ++ks) {
        bf16x8 a = *(const bf16x8*)&hS[(wave * 16 + m16) * HROW + ks * 32 + quad * 8];
        #pragma unroll
        for (int ct = 0; ct < 8; ++ct) {
            bf16x8 b = *(const bf16x8*)&W2T[(ct * 16 + m16) * HIDDEN + ks * 32 + quad * 8];
            acc[ct] = __builtin_amdgcn_mfma_f32_16x16x32_bf16(a, b, acc[ct], 0, 0, 0);
        }
    }

    // epilogue B: BN (folded) + store fp32
    #pragma unroll
    for (int ct = 0; ct < 8; ++ct) {
        int col = ct * 16 + m16;
        float sc = scf[col], sh = shf[col];
        #pragma unroll
        for (int r = 0; r < 4; ++r) {
            int grow = row0 + quad * 4 + r;
            if (grow < N)
                io[(size_t)grow * HIDDEN + col] = fmaf(acc[ct][r], sc, sh);
        }
    }
}

// fp32-A variant (tier B/C): in-place on io
__global__ __launch_bounds__(256) void mlp_mfma_kernel(
    float* io,
    const short* __restrict__ W1T, const short* __restrict__ W2T,
    const float* __restrict__ bi1,
    const float* __restrict__ scf, const float* __restrict__ shf,
    int N) {
    __shared__ short hS[64 * HROW];

    const int t = threadIdx.x;
    const int wave = t >> 6;
    const int lane = t & 63;
    const int quad = lane >> 4;
    const int m16  = lane & 15;
    const int row0 = blockIdx.x * 64 + wave * 16;
    const int arow = row0 + m16;

    f32x4 acc[8];
    #pragma unroll
    for (int ct = 0; ct < 8; ++ct) acc[ct] = (f32x4)(0.f);

    #pragma unroll
    for (int ks = 0; ks < 4; ++ks) {
        bf16x8 a;
        if (arow < N) {
            const float* ap = &io[(size_t)arow * HIDDEN + ks * 32 + quad * 8];
            float4 v0 = *(const float4*)ap;
            float4 v1 = *(const float4*)(ap + 4);
            a[0] = f2bf(v0.x); a[1] = f2bf(v0.y); a[2] = f2bf(v0.z); a[3] = f2bf(v0.w);
            a[4] = f2bf(v1.x); a[5] = f2bf(v1.y); a[6] = f2bf(v1.z); a[7] = f2bf(v1.w);
        } else {
            #pragma unroll
            for (int j = 0; j < 8; ++j) a[j] = 0;
        }
        #pragma unroll
        for (int ct = 0; ct < 8; ++ct) {
            bf16x8 b = *(const bf16x8*)&W1T[(ct * 16 + m16) * HIDDEN + ks * 32 + quad * 8];
            acc[ct] = __builtin_amdgcn_mfma_f32_16x16x32_bf16(a, b, acc[ct], 0, 0, 0);
        }
    }

    #pragma unroll
    for (int ct = 0; ct < 8; ++ct) {
        int col = ct * 16 + m16;
        float b1 = bi1[col];
        #pragma unroll
        for (int r = 0; r < 4; ++r) {
            int lrow = wave * 16 + quad * 4 + r;
            float v = acc[ct][r] + b1;
            float h = (v > 20.f) ? v : log1pf(__expf(v));
            hS[lrow * HROW + col] = f2bf(h);
            acc[ct][r] = 0.f;
        }
    }
    __syncthreads();

    #pragma unroll
    for (int ks = 0; ks < 4; ++ks) {
        bf16x8 a = *(const bf16x8*)&hS[(wave * 16 + m16) * HROW + ks * 32 + quad * 8];
        #pragma unroll
        for (int ct = 0; ct < 8; ++ct) {
            bf16x8 b = *(const bf16x8*)&W2T[(ct * 16 + m16) * HIDDEN + ks * 32 + quad * 8];
            acc[ct] = __builtin_amdgcn_mfma_f32_16x16x32_bf16(a, b, acc[ct], 0, 0, 0);
        }
    }

    #pragma unroll
    for (int ct = 0; ct < 8; ++ct) {
        int col = ct * 16 + m16;
        float sc = scf[col], sh = shf[col];
        #pragma unroll
        for (int r = 0; r < 4; ++r) {
            int grow = row0 + quad * 4 + r;
            if (grow < N)
                io[(size_t)grow * HIDDEN + col] = fmaf(acc[ct][r], sc, sh);
        }
    }
}

// ---------------------------------------------------------------------------
// Fallback path kernels (tiny ws): atomic scatter + fp32 vector MLP
// ---------------------------------------------------------------------------
__global__ void edge_filter_kernel(const float* __restrict__ ew,
                                   const float* __restrict__ Wf1, const float* __restrict__ bf1,
                                   const float* __restrict__ wsum, const float* __restrict__ bsum,
                                   float* __restrict__ fs, int E) {
    __shared__ float sW[NFILT], sB[NFILT], sS[NFILT];
    if (threadIdx.x < NFILT) {
        sW[threadIdx.x] = Wf1[threadIdx.x];
        sB[threadIdx.x] = bf1[threadIdx.x];
        sS[threadIdx.x] = wsum[threadIdx.x];
    }
    __syncthreads();
    int e = blockIdx.x * blockDim.x + threadIdx.x;
    if (e >= E) return;
    fs[e] = edge_coeff(ew[e], sW, sB, sS, *bsum);
}

__global__ void scatter_kernel(const int* __restrict__ rows, const int* __restrict__ cols,
                               const float* __restrict__ x, const float* __restrict__ fs,
                               float* __restrict__ agg, int E) {
    int t = threadIdx.x;
    int e = blockIdx.x * 8 + (t >> 5);
    if (e >= E) return;
    int lane = t & 31;
    int r = rows[e];
    int c = cols[e];
    float f = fs[e];
    const float4 xv = *(const float4*)&x[c * HIDDEN + lane * 4];
    float* dst = &agg[r * HIDDEN + lane * 4];
    atomicAdd(dst + 0, xv.x * f);
    atomicAdd(dst + 1, xv.y * f);
    atomicAdd(dst + 2, xv.z * f);
    atomicAdd(dst + 3, xv.w * f);
}

__global__ __launch_bounds__(256) void mlp_kernel(
    float* __restrict__ io,
    const float* __restrict__ Wi1, const float* __restrict__ bi1,
    const float* __restrict__ Wi2, const float* __restrict__ bi2,
    const float* __restrict__ gamma, const float* __restrict__ beta,
    const float* __restrict__ mean, const float* __restrict__ var,
    int N) {
    __shared__ float As[64 * HIDDEN];
    __shared__ float Wh[64 * HIDDEN];

    const int t = threadIdx.x;
    const int row0 = blockIdx.x * 64;
    const int col4 = (t & 31) * 4;
    const int rgrp = t >> 5;

    #pragma unroll
    for (int i = 0; i < 8; ++i) {
        int f4 = t + 256 * i;
        int r = f4 >> 5, c4 = (f4 & 31) * 4;
        int node = row0 + r;
        float4 v = make_float4(0.f, 0.f, 0.f, 0.f);
        if (node < N) v = *(const float4*)&io[node * HIDDEN + c4];
        *(float4*)&As[r * HIDDEN + c4] = v;
    }

    float acc[8][4];
    #pragma unroll
    for (int r = 0; r < 8; ++r)
        for (int j = 0; j < 4; ++j) acc[r][j] = 0.f;

    for (int kh = 0; kh < 2; ++kh) {
        __syncthreads();
        #pragma unroll
        for (int i = 0; i < 8; ++i) {
            int f4 = t + 256 * i;
            int kr = f4 >> 5, c4 = (f4 & 31) * 4;
            *(float4*)&Wh[kr * HIDDEN + c4] = *(const float4*)&Wi1[(kh * 64 + kr) * HIDDEN + c4];
        }
        __syncthreads();
        for (int k = 0; k < 64; ++k) {
            float4 w = *(const float4*)&Wh[k * HIDDEN + col4];
            #pragma unroll
            for (int r = 0; r < 8; ++r) {
                float a = As[(rgrp + 8 * r) * HIDDEN + kh * 64 + k];
                acc[r][0] = fmaf(a, w.x, acc[r][0]);
                acc[r][1] = fmaf(a, w.y, acc[r][1]);
                acc[r][2] = fmaf(a, w.z, acc[r][2]);
                acc[r][3] = fmaf(a, w.w, acc[r][3]);
            }
        }
    }
    __syncthreads();

    {
        float4 b = *(const float4*)&bi1[col4];
        float bv[4] = {b.x, b.y, b.z, b.w};
        #pragma unroll
        for (int r = 0; r < 8; ++r) {
            float hv[4];
            #pragma unroll
            for (int j = 0; j < 4; ++j) {
                float v = acc[r][j] + bv[j];
                hv[j] = (v > 20.f) ? v : log1pf(__expf(v));
                acc[r][j] = 0.f;
            }
            *(float4*)&As[(rgrp + 8 * r) * HIDDEN + col4] =
                make_float4(hv[0], hv[1], hv[2], hv[3]);
        }
    }

    for (int kh = 0; kh < 2; ++kh) {
        __syncthreads();
        #pragma unroll
        for (int i = 0; i < 8; ++i) {
            int f4 = t + 256 * i;
            int kr = f4 >> 5, c4 = (f4 & 31) * 4;
            *(float4*)&Wh[kr * HIDDEN + c4] = *(const float4*)&Wi2[(kh * 64 + kr) * HIDDEN + c4];
        }
        __syncthreads();
        for (int k = 0; k < 64; ++k) {
            float4 w = *(const float4*)&Wh[k * HIDDEN + col4];
            #pragma unroll
            for (int r = 0; r < 8; ++r) {
                float a = As[(rgrp + 8 * r) * HIDDEN + kh * 64 + k];
                acc[r][0] = fmaf(a, w.x, acc[r][0]);
                acc[r][1] = fmaf(a, w.y, acc[r][1]);
                acc[r][2] = fmaf(a, w.z, acc[r][2]);
                acc[r][3] = fmaf(a, w.w, acc[r][3]);
            }
        }
    }

    {
        float4 b2 = *(const float4*)&bi2[col4];
        float4 g  = *(const float4*)&gamma[col4];
        float4 be = *(const float4*)&beta[col4];
        float4 mu = *(const float4*)&mean[col4];
        float4 va = *(const float4*)&var[col4];
        float bv[4]  = {b2.x, b2.y, b2.z, b2.w};
        float gv[4]  = {g.x, g.y, g.z, g.w};
        float bev[4] = {be.x, be.y, be.z, be.w};
        float muv[4] = {mu.x, mu.y, mu.z, mu.w};
        float vav[4] = {va.x, va.y, va.z, va.w};
        float sc[4];
        #pragma unroll
        for (int j = 0; j < 4; ++j) sc[j] = gv[j] * rsqrtf(vav[j] + 1e-3f);
        #pragma unroll
        for (int r = 0; r < 8; ++r) {
            int node = row0 + rgrp + 8 * r;
            if (node < N) {
                float o[4];
                #pragma unroll
                for (int j = 0; j < 4; ++j)
                    o[j] = (acc[r][j] + bv[j] - muv[j]) * sc[j] + bev[j];
                *(float4*)&io[node * HIDDEN + col4] = make_float4(o[0], o[1], o[2], o[3]);
            }
        }
    }
}

extern "C" void kernel_launch(void* const* d_in, const int* in_sizes, int n_in,
                              void* d_out, int out_size, void* d_ws, size_t ws_size,
                              hipStream_t stream) {
    const float* x    = (const float*)d_in[0];
    const int*   ei   = (const int*)d_in[1];
    const float* ew   = (const float*)d_in[2];
    // d_in[3] = edge_attr: unused by the reference math
    const float* Wf1  = (const float*)d_in[4];
    const float* bf1  = (const float*)d_in[5];
    const float* Wf2  = (const float*)d_in[6];
    const float* bf2  = (const float*)d_in[7];
    const float* Wi1  = (const float*)d_in[8];
    const float* bi1  = (const float*)d_in[9];
    const float* Wi2  = (const float*)d_in[10];
    const float* bi2  = (const float*)d_in[11];
    const float* gam  = (const float*)d_in[12];
    const float* bet  = (const float*)d_in[13];
    const float* mmu  = (const float*)d_in[14];
    const float* mva  = (const float*)d_in[15];

    const int N = in_sizes[0] / HIDDEN;
    const int E = in_sizes[2];
    const int* rows = ei;
    const int* cols = ei + E;

    float* io = (float*)d_out;     // final output; tier B/C also use it as agg

    const int B = (N + SCAN_B - 1) / SCAN_B;

    // ws layout:
    //   deg[N] | offs[N+1] | bsums[B] | wsum[64] | bsum[1] | lut[LUTK+1] | pad |
    //   epack[E] int2 | pad | W1T | W2T | scf[128] | shf[128] | pad |
    //   rank[E] | pad | xh[N*128] bf16 | aggh[N*128] bf16
    char* ws = (char*)d_ws;
    int*   deg    = (int*)ws;
    int*   offs   = deg + N;
    int*   bsums  = offs + N + 1;
    float* wsumv  = (float*)(bsums + B);
    float* bsumv  = wsumv + NFILT;
    float* lut    = bsumv + 1;
    size_t hdr_ints  = (size_t)(2 * N + 1 + B + NFILT + 1 + LUTK + 1);
    size_t epack_off = ((hdr_ints * 4) + 15) & ~(size_t)15;
    int2*  epack  = (int2*)(ws + epack_off);
    size_t wT_off = (epack_off + (size_t)E * sizeof(int2) + 15) & ~(size_t)15;
    short* W1T    = (short*)(ws + wT_off);
    short* W2T    = W1T + HIDDEN * HIDDEN;
    float* scf    = (float*)(W2T + HIDDEN * HIDDEN);
    float* shf    = scf + HIDDEN;
    size_t base_need = wT_off + 2 * HIDDEN * HIDDEN * sizeof(short) + 2 * HIDDEN * sizeof(float);
    size_t rank_off  = (base_need + 15) & ~(size_t)15;
    int*   rank   = (int*)(ws + rank_off);
    size_t rank_need = rank_off + (size_t)E * sizeof(int);
    size_t xh_off    = (rank_need + 15) & ~(size_t)15;
    short* xh     = (short*)(ws + xh_off);
    short* aggh   = xh + (size_t)N * HIDDEN;
    size_t bf_need = xh_off + 2 * (size_t)N * HIDDEN * sizeof(short);

    if (ws_size >= base_need && B <= SCAN_B) {
        const bool use_rank = (ws_size >= rank_need);
        const bool use_bf   = (ws_size >= bf_need);   // implies use_rank
        hipMemsetAsync(deg, 0, (size_t)N * sizeof(int), stream);
        wsum_kernel<<<1, 64, 0, stream>>>(Wf2, bf2, wsumv, bsumv);
        lut_kernel<<<(LUTK + 256) / 256, 256, 0, stream>>>(Wf1, bf1, wsumv, bsumv, lut);
        prep_w_kernel<<<128, 256, 0, stream>>>(Wi1, Wi2, W1T, W2T);
        prep_bn_kernel<<<1, HIDDEN, 0, stream>>>(bi2, gam, bet, mmu, mva, scf, shf);
        if (use_bf) {
            int total8 = N * (HIDDEN / 8);
            x2bf_kernel<<<(total8 + 255) / 256, 256, 0, stream>>>(x, xh, total8);
        }
        if (use_rank)
            count_rank_kernel<<<(E + 255) / 256, 256, 0, stream>>>(rows, deg, rank, E);
        else
            count_kernel<<<(E + 255) / 256, 256, 0, stream>>>(rows, deg, E);
        scan_p1<<<B, SCAN_B, 0, stream>>>(deg, bsums, N);
        scan_p2<<<1, SCAN_B, 0, stream>>>(bsums, B);
        if (use_rank) {
            scan_p3_t<false><<<B, SCAN_B, 0, stream>>>(deg, bsums, offs, N);
            fill_rank_kernel<<<(E + 255) / 256, 256, 0, stream>>>(rows, cols, ew, rank,
                                                                  offs, lut, epack, E);
        } else {
            scan_p3_t<true><<<B, SCAN_B, 0, stream>>>(deg, bsums, offs, N);
            fill_cursor_kernel<<<(E + 255) / 256, 256, 0, stream>>>(rows, cols, ew, deg,
                                                                    lut, epack, E);
        }
        if (use_bf) {
            gather_bf_kernel<<<(N + 7) / 8, 256, 0, stream>>>(offs, epack, xh, aggh, N);
            mlp_mfma_bf_kernel<<<(N + 63) / 64, 256, 0, stream>>>(aggh, io, W1T, W2T,
                                                                  bi1, scf, shf, N);
        } else {
            gather_kernel<<<(N + 7) / 8, 256, 0, stream>>>(offs, epack, x, io, N);
            mlp_mfma_kernel<<<(N + 63) / 64, 256, 0, stream>>>(io, W1T, W2T, bi1, scf, shf, N);
        }
    } else {
        // ---- fallback: atomic scatter + fp32 MLP ----
        float* fs = (float*)d_ws;             // [E]
        float* w2 = fs + E;                   // [64]
        float* b2 = w2 + NFILT;               // [1]
        hipMemsetAsync(d_out, 0, (size_t)out_size * sizeof(float), stream);
        wsum_kernel<<<1, 64, 0, stream>>>(Wf2, bf2, w2, b2);
        edge_filter_kernel<<<(E + 255) / 256, 256, 0, stream>>>(ew, Wf1, bf1, w2, b2, fs, E);
        scatter_kernel<<<(E + 7) / 8, 256, 0, stream>>>(rows, cols, x, fs, io, E);
        mlp_kernel<<<(N + 63) / 64, 256, 0, stream>>>(io, Wi1, bi1, Wi2, bi2,
                                                      gam, bet, mmu, mva, N);
    }
}